// Round 4
// baseline (430.007 us; speedup 1.0000x reference)
//
#include <hip/hip_runtime.h>
#include <hip/hip_bf16.h>
#include <stdint.h>

// Problem constants (fixed by the reference)
#define NN    20000      // nodes
#define NP    20096      // nodes padded to 157*128 (garbage rows never read back)
#define EE    320000     // edges (w/o self loops)
#define CH    128        // feature width per gate
#define GC    512        // 4 gates * 128
#define NHtot 2560000    // N*CH

typedef short bf16x8 __attribute__((ext_vector_type(8)));   // 8 bf16 (4 VGPRs)
typedef float f32x4  __attribute__((ext_vector_type(4)));   // 4 fp32 acc

// ---------- bf16 helpers ----------
__device__ __forceinline__ unsigned short f2bf(float f) {
    __hip_bfloat16 b = __float2bfloat16(f);           // RNE
    union { __hip_bfloat16 b; unsigned short u; } c; c.b = b; return c.u;
}
// fast bf16x2 dword -> two f32: lo = u<<16, hi = u & 0xffff0000 (1 VALU op each)
__device__ __forceinline__ void fma4(uint2 u, float n, float* acc) {
    union { unsigned int i; float f; } t;
    t.i = u.x << 16;         acc[0] += n * t.f;
    t.i = u.x & 0xffff0000u; acc[1] += n * t.f;
    t.i = u.y << 16;         acc[2] += n * t.f;
    t.i = u.y & 0xffff0000u; acc[3] += n * t.f;
}
__device__ __forceinline__ void fma8(uint4 u, float n, float* acc) {
    union { unsigned int i; float f; } t;
    t.i = u.x << 16;         acc[0] += n * t.f;
    t.i = u.x & 0xffff0000u; acc[1] += n * t.f;
    t.i = u.y << 16;         acc[2] += n * t.f;
    t.i = u.y & 0xffff0000u; acc[3] += n * t.f;
    t.i = u.z << 16;         acc[4] += n * t.f;
    t.i = u.z & 0xffff0000u; acc[5] += n * t.f;
    t.i = u.w << 16;         acc[6] += n * t.f;
    t.i = u.w & 0xffff0000u; acc[7] += n * t.f;
}
__device__ __forceinline__ void tof4(uint2 u, float* f) {
    union { unsigned int i; float f; } t;
    t.i = u.x << 16;         f[0] = t.f;
    t.i = u.x & 0xffff0000u; f[1] = t.f;
    t.i = u.y << 16;         f[2] = t.f;
    t.i = u.y & 0xffff0000u; f[3] = t.f;
}
__device__ __forceinline__ void tof8(uint4 u, float* f) {
    union { unsigned int i; float f; } t;
    t.i = u.x << 16;         f[0] = t.f;
    t.i = u.x & 0xffff0000u; f[1] = t.f;
    t.i = u.y << 16;         f[2] = t.f;
    t.i = u.y & 0xffff0000u; f[3] = t.f;
    t.i = u.z << 16;         f[4] = t.f;
    t.i = u.z & 0xffff0000u; f[5] = t.f;
    t.i = u.w << 16;         f[6] = t.f;
    t.i = u.w & 0xffff0000u; f[7] = t.f;
}
__device__ __forceinline__ uint2 pack4(const float* f) {
    uint2 v;
    v.x = (unsigned int)f2bf(f[0]) | ((unsigned int)f2bf(f[1]) << 16);
    v.y = (unsigned int)f2bf(f[2]) | ((unsigned int)f2bf(f[3]) << 16);
    return v;
}
// async 16B global -> LDS (lane deposits at lds_base + lane*16)
__device__ __forceinline__ void gload_lds16(const void* g, void* l) {
    __builtin_amdgcn_global_load_lds(
        (const __attribute__((address_space(1))) void*)g,
        (__attribute__((address_space(3))) void*)l, 16, 0, 0);
}

// ---------- 1. MERGED: edge count (int atomics) + weight prep + btot ----------
// blocks [0,1250): count; blocks [1250,2274): transpose/cast weights (+btot).
// btot is written PRE-PERMUTED into the interleaved Sb layout:
//   pos = (hh>>4)*64 + g*16 + (hh&15)   for source index f = g*128+hh.
__global__ void k_cntprep(const int* __restrict__ ei, int* __restrict__ cnt,
                          const float* __restrict__ W0, const float* __restrict__ W1,
                          const float* __restrict__ W2, const float* __restrict__ W3,
                          unsigned short* __restrict__ T0, unsigned short* __restrict__ T1,
                          unsigned short* __restrict__ T2, unsigned short* __restrict__ T3,
                          const float* __restrict__ bx1, const float* __restrict__ bh1,
                          const float* __restrict__ bg, float* __restrict__ btot) {
    int bid = blockIdx.x;
    if (bid < EE / 256) {
        int e = bid * 256 + threadIdx.x;
        atomicAdd(&cnt[ei[EE + e]], 1);
        return;
    }
    int pid = bid - EE / 256;                        // 0..1023
    int z = pid >> 8, y = (pid >> 6) & 3, xb = pid & 63;
    if (z == 0 && y == 0 && xb < 2) {
        int f = xb * 256 + threadIdx.x;              // 512 entries, f = g*128+hh
        int g = f >> 7, hh = f & 127;
        int pos = ((hh >> 4) << 6) | (g << 4) | (hh & 15);
        btot[pos] = bx1[f] + bh1[f] + bg[f];
    }
    const float* W; unsigned short* T;
    switch (z) {
        case 0:  W = W0; T = T0; break;
        case 1:  W = W1; T = T1; break;
        case 2:  W = W2; T = T2; break;
        default: W = W3; T = T3; break;
    }
    int n = xb * 2 + (threadIdx.x >> 7);
    int k = threadIdx.x & 127;
    T[((size_t)y * 128 + n) * 128 + k] = f2bf(W[((size_t)y * 128 + k) * 128 + n]);
}

// ---------- 2. hierarchical exclusive scan of counts ----------
__global__ void k_scan1(const int* __restrict__ cnt, int* __restrict__ rowoff,
                        int* __restrict__ bsum) {
    __shared__ int wsum[4];
    int i = blockIdx.x * 256 + threadIdx.x;
    int self = (i < NN) ? cnt[i] : 0;
    int lane = threadIdx.x & 63, wid = threadIdx.x >> 6;
    int v = self;
    #pragma unroll
    for (int off = 1; off < 64; off <<= 1) {
        int u = __shfl_up(v, off);
        if (lane >= off) v += u;
    }
    if (lane == 63) wsum[wid] = v;
    __syncthreads();
    int wof = 0;
    for (int k = 0; k < wid; ++k) wof += wsum[k];
    if (i < NN) rowoff[i] = wof + v - self;
    if (threadIdx.x == 255) bsum[blockIdx.x] = wof + v;
}

__global__ void k_scan2(int* __restrict__ bsum) {
    int lane = threadIdx.x;                          // 64 threads
    int base = 0;
    for (int start = 0; start < 80; start += 64) {
        int i = start + lane;
        int self = (i < 80) ? bsum[i] : 0;
        int v = self;
        #pragma unroll
        for (int off = 1; off < 64; off <<= 1) {
            int u = __shfl_up(v, off);
            if (lane >= off) v += u;
        }
        if (i < 80) bsum[i] = base + v - self;
        base += __shfl(v, 63);
    }
}

__global__ void k_scan3(int* __restrict__ rowoff, const int* __restrict__ bsum,
                        int* __restrict__ cur) {
    int i = blockIdx.x * 256 + threadIdx.x;
    if (i < NN) {
        int v = rowoff[i] + bsum[i >> 8];
        rowoff[i] = v; cur[i] = v;
    }
    if (i == NN) rowoff[NN] = EE;
}

// ---------- 3. scatter edges into CSR with RAW weights ----------
__global__ void k_scatter(const int* __restrict__ ei, const float* __restrict__ ew,
                          int* __restrict__ cur,
                          int* __restrict__ csrs, float* __restrict__ csrw) {
    int e = blockIdx.x * 256 + threadIdx.x;
    if (e >= EE) return;
    int s = ei[e], d = ei[EE + e];
    int p = atomicAdd(&cur[d], 1);
    csrs[p] = s; csrw[p] = ew[e];
}

// ---------- 4. FUSED: degree row-sum -> dis -> scale & pack x|h to bf16 ----------
__global__ __launch_bounds__(256) void k_degcast(
        const float* __restrict__ x, const float* __restrict__ h,
        const int* __restrict__ rowoff, const float* __restrict__ csrw,
        float* __restrict__ dis, unsigned short* __restrict__ xhb) {
    int wid = threadIdx.x >> 6, lane = threadIdx.x & 63;
    int w = blockIdx.x * 4 + wid;                    // grid exact: NN/4
    int e0 = rowoff[w], e1 = rowoff[w + 1];
    float s = 0.f;
    for (int e = e0 + lane; e < e1; e += 64) s += csrw[e];
    #pragma unroll
    for (int off = 32; off; off >>= 1) s += __shfl_xor(s, off);
    float dn = rsqrtf(fmaxf(1.0f + s, 1e-12f));      // self-loop weight 1
    if (lane == 0) dis[w] = dn;
    const float* src = (lane < 32) ? x + (size_t)w * CH + lane * 4
                                   : h + (size_t)w * CH + (lane - 32) * 4;
    float4 v = *(const float4*)src;
    float f[4] = { dn * v.x, dn * v.y, dn * v.z, dn * v.w };
    *(uint2*)(xhb + (size_t)w * 256 + lane * 4) = pack4(f);
}

// ---------- 5. XCD-chunked prop over 256-wide bf16 rows (table pre-scaled) ----------
// chunk = bid&3 (4 chunks x 128 B slice of each 512 B row). Blocks with chunk c
// land on XCDs {c, c+4} -> per-XCD gather footprint = NP*128B = 2.57 MB (L2-fit).
// Wave = 1 node: 8 lane-groups x 8 lanes x uint4 gather 8 EDGES per load instr.
__global__ __launch_bounds__(256) void k_prop256c(
        const unsigned short* __restrict__ tab, unsigned short* __restrict__ o,
        const int* __restrict__ rowoff, const int* __restrict__ csrs,
        const float* __restrict__ csrw, const float* __restrict__ dis) {
    int chunk = blockIdx.x & 3;
    int w = (blockIdx.x >> 2) * 4 + (threadIdx.x >> 6);   // grid exact: (NN/4)*4
    int l = threadIdx.x & 63, grp = l >> 3, li = l & 7;
    const uint4* T4 = (const uint4*)tab;             // row = 32 uint4 = 512 B
    int coff = chunk * 8 + li;                       // uint4 offset within row
    float acc[8];
    #pragma unroll
    for (int j = 0; j < 8; ++j) acc[j] = 0.f;
    if (grp == 0) tof8(T4[(size_t)w * 32 + coff], acc);   // self term once
    int e = rowoff[w], e1 = rowoff[w + 1];
    for (; e + 16 <= e1; e += 16) {                  // 2 x 8-edge batches in flight
        int   sA = csrs[e + grp],  sB = csrs[e + 8 + grp];
        float nA = csrw[e + grp],  nB = csrw[e + 8 + grp];
        uint4 uA = T4[(size_t)sA * 32 + coff];
        uint4 uB = T4[(size_t)sB * 32 + coff];
        fma8(uA, nA, acc); fma8(uB, nB, acc);
    }
    for (; e + 8 <= e1; e += 8) {
        int s = csrs[e + grp]; float n = csrw[e + grp];
        fma8(T4[(size_t)s * 32 + coff], n, acc);
    }
    if (grp < e1 - e) {                              // tail: rem in [0,8)
        int s = csrs[e + grp]; float n = csrw[e + grp];
        fma8(T4[(size_t)s * 32 + coff], n, acc);
    }
    #pragma unroll
    for (int j = 0; j < 8; ++j) {                    // cross-group reduce (bits 3..5)
        acc[j] += __shfl_xor(acc[j], 8);
        acc[j] += __shfl_xor(acc[j], 16);
        acc[j] += __shfl_xor(acc[j], 32);
    }
    if (grp == 0) {
        float dw = dis[w];
        #pragma unroll
        for (int j = 0; j < 8; ++j) acc[j] *= dw;
        uint2 p0 = pack4(acc), p1 = pack4(acc + 4);
        uint4 ov; ov.x = p0.x; ov.y = p0.y; ov.z = p1.x; ov.w = p1.y;
        ((uint4*)o)[(size_t)w * 32 + coff] = ov;     // linear layout (gemm1 input)
    }
}

// ---------- MFMA GEMM shared machinery ----------
// LDS chunk id = r*16 + cc holds GLOBAL chunk (r, cc ^ (r&15)).  Staging via
// global_load_lds (lane-contiguous LDS) with the XOR applied on the GLOBAL
// index; fragment reads use SWZ as before -> zero bank conflicts.
#define SWZ(r, c8) (((r) << 4) + ((c8) ^ ((r) & 15)))

// ---------- 6. GEMM1 (both sides in one launch via blockIdx.z) ----------
// h0 = relu(axh[:, side] @ W0[g] + b0[g]) -> bf16 [NP,512]
__global__ __launch_bounds__(256) void k_gemm1(
        const unsigned short* __restrict__ A,
        const unsigned short* __restrict__ Wtx, const unsigned short* __restrict__ Wth,
        const float* __restrict__ bx0, const float* __restrict__ bh0,
        unsigned short* __restrict__ outx, unsigned short* __restrict__ outh) {
    __shared__ uint4 As[2048];                       // 32 KB
    __shared__ uint4 Bs[2048];                       // 32 KB
    const int side = blockIdx.z;
    const int aoff = side * 128;
    const unsigned short* Wt = side ? Wth : Wtx;
    const float* bias        = side ? bh0 : bx0;
    unsigned short* out      = side ? outh : outx;

    const int    g    = blockIdx.y;
    const size_t row0 = (size_t)blockIdx.x * 128;
    const int    t    = threadIdx.x;
    const int    wv   = t >> 6;                      // wave id (LDS base uniform)
    const unsigned short* Wg = Wt + (size_t)g * 16384;   // [n][k] bf16

    #pragma unroll
    for (int p = 0; p < 8; ++p) {                    // async stage A and W tiles
        int id = t + 256 * p, r = id >> 4, cc = id & 15;
        int c8 = cc ^ (r & 15);                      // XOR swizzle on global side
        gload_lds16(A + (row0 + r) * 256 + aoff + c8 * 8, &As[p * 256 + wv * 64]);
        gload_lds16(Wg + r * CH + c8 * 8,                 &Bs[p * 256 + wv * 64]);
    }
    __syncthreads();                                 // vmcnt(0) drain at barrier

    const int l = t & 63;
    const int m0 = (wv >> 1) * 64, n0 = (wv & 1) * 64;
    const int lm = l & 15, q = l >> 4;
    f32x4 acc[4][4];
    #pragma unroll
    for (int i = 0; i < 4; ++i)
        #pragma unroll
        for (int j = 0; j < 4; ++j) { acc[i][j][0]=0.f; acc[i][j][1]=0.f; acc[i][j][2]=0.f; acc[i][j][3]=0.f; }

    #pragma unroll
    for (int kc = 0; kc < 4; ++kc) {
        int c8 = kc * 4 + q;
        bf16x8 a[4], b[4];
        #pragma unroll
        for (int i = 0; i < 4; ++i) { int r = m0 + i * 16 + lm; a[i] = *(const bf16x8*)&As[SWZ(r, c8)]; }
        #pragma unroll
        for (int j = 0; j < 4; ++j) { int r = n0 + j * 16 + lm; b[j] = *(const bf16x8*)&Bs[SWZ(r, c8)]; }
        #pragma unroll
        for (int i = 0; i < 4; ++i)
            #pragma unroll
            for (int j = 0; j < 4; ++j)
                acc[i][j] = __builtin_amdgcn_mfma_f32_16x16x32_bf16(a[i], b[j], acc[i][j], 0, 0, 0);
    }

    #pragma unroll
    for (int j = 0; j < 4; ++j) {
        float bb = bias[g * CH + n0 + j * 16 + lm];
        #pragma unroll
        for (int i = 0; i < 4; ++i)
            #pragma unroll
            for (int r = 0; r < 4; ++r) {
                int rowl = m0 + i * 16 + q * 4 + r;   // C/D: row=(lane>>4)*4+reg
                int col  = n0 + j * 16 + lm;          //      col=lane&15
                out[(row0 + rowl) * GC + g * CH + col] = f2bf(fmaxf(acc[i][j][r] + bb, 0.f));
            }
    }
}

// ---------- 7. GEMM2 (fused): Sb = dis .* (h0x@Wx1 + h0h@Wh1) -> bf16 [NP,512] ----------
// OUTPUT LAYOUT (for XCD-chunked prop): col = (hh>>4)*64 + g*16 + (hh&15)
// i.e. row = 8 feature-groups of 128 B, each holding 16 feats x all 4 gates.
__global__ __launch_bounds__(256) void k_gemm2(
        const unsigned short* __restrict__ A1, const unsigned short* __restrict__ A2,
        const unsigned short* __restrict__ Wt1, const unsigned short* __restrict__ Wt2,
        const float* __restrict__ dis, unsigned short* __restrict__ outS) {
    __shared__ uint4 As[2048];
    __shared__ uint4 Bs[2048];
    const int    g    = blockIdx.y;
    const size_t row0 = (size_t)blockIdx.x * 128;
    const int    t    = threadIdx.x;
    const int    wv   = t >> 6;
    const int l = t & 63;
    const int m0 = (wv >> 1) * 64, n0 = (wv & 1) * 64;
    const int lm = l & 15, q = l >> 4;
    f32x4 acc[4][4];
    #pragma unroll
    for (int i = 0; i < 4; ++i)
        #pragma unroll
        for (int j = 0; j < 4; ++j) { acc[i][j][0]=0.f; acc[i][j][1]=0.f; acc[i][j][2]=0.f; acc[i][j][3]=0.f; }

    for (int side = 0; side < 2; ++side) {
        if (side) __syncthreads();                   // all waves done reading LDS
        const unsigned short* Ap = side ? A2 : A1;
        const unsigned short* Wg = (side ? Wt2 : Wt1) + (size_t)g * 16384;
        #pragma unroll
        for (int p = 0; p < 8; ++p) {                // async stage A and W tiles
            int id = t + 256 * p, r = id >> 4, cc = id & 15;
            int c8 = cc ^ (r & 15);
            gload_lds16(Ap + (row0 + r) * GC + g * CH + c8 * 8, &As[p * 256 + wv * 64]);
            gload_lds16(Wg + r * CH + c8 * 8,                   &Bs[p * 256 + wv * 64]);
        }
        __syncthreads();
        #pragma unroll
        for (int kc = 0; kc < 4; ++kc) {
            int c8 = kc * 4 + q;
            bf16x8 a[4], b[4];
            #pragma unroll
            for (int i = 0; i < 4; ++i) { int r = m0 + i * 16 + lm; a[i] = *(const bf16x8*)&As[SWZ(r, c8)]; }
            #pragma unroll
            for (int j = 0; j < 4; ++j) { int r = n0 + j * 16 + lm; b[j] = *(const bf16x8*)&Bs[SWZ(r, c8)]; }
            #pragma unroll
            for (int i = 0; i < 4; ++i)
                #pragma unroll
                for (int j = 0; j < 4; ++j)
                    acc[i][j] = __builtin_amdgcn_mfma_f32_16x16x32_bf16(a[i], b[j], acc[i][j], 0, 0, 0);
        }
    }

    #pragma unroll
    for (int j = 0; j < 4; ++j) {
        int fh = (n0 + j * 16) >> 4;                 // feature-group (in-gate col / 16)
        #pragma unroll
        for (int i = 0; i < 4; ++i)
            #pragma unroll
            for (int r = 0; r < 4; ++r) {
                int rowl = m0 + i * 16 + q * 4 + r;
                float dr = dis[row0 + rowl];         // pre-scale for prop
                outS[(row0 + rowl) * GC + fh * 64 + g * 16 + lm] = f2bf(dr * acc[i][j][r]);
            }
    }
}

// ---------- 8. XCD-chunked prop over interleaved Sb + FUSED LSTM gates ----------
// chunk = bid&7 == XCD; per-XCD gather footprint = NP*128B = 2.57 MB (L2-fit).
// Wave = 1 node: 8 lane-groups x 8 lanes x uint4 -> 8 EDGES per gather instr
// (restores 16B/lane vs round-1's 2B/lane scalar gathers).
// Lane (grp,li) covers within-chunk cols c = 8*li+j (j<8): gate g = li>>1,
// lo = 8*(li&1)+j. Gate fusion: shfl_xor on li bits 1..2 (xor 2/4/6).
__global__ __launch_bounds__(256) void k_prop512v(
        const unsigned short* __restrict__ Sb, float* __restrict__ out,
        const int* __restrict__ rowoff, const int* __restrict__ csrs,
        const float* __restrict__ csrw, const float* __restrict__ dis,
        const float* __restrict__ c, const float* __restrict__ btot,
        const float* __restrict__ wc) {
    int chunk = blockIdx.x & 7;
    int w = (blockIdx.x >> 3) * 4 + (threadIdx.x >> 6);   // grid exact: (NN/4)*8
    int l = threadIdx.x & 63, grp = l >> 3, li = l & 7;
    const uint4* S4 = (const uint4*)Sb;              // row = 64 uint4 = 1 KB
    int coff = chunk * 8 + li;                       // uint4 offset within row
    float acc[8];
    #pragma unroll
    for (int j = 0; j < 8; ++j) acc[j] = 0.f;
    if (grp == 0) tof8(S4[(size_t)w * 64 + coff], acc);   // self term once
    int e = rowoff[w], e1 = rowoff[w + 1];
    for (; e + 16 <= e1; e += 16) {                  // 2 x 8-edge batches in flight
        int   sA = csrs[e + grp],  sB = csrs[e + 8 + grp];
        float nA = csrw[e + grp],  nB = csrw[e + 8 + grp];
        uint4 uA = S4[(size_t)sA * 64 + coff];
        uint4 uB = S4[(size_t)sB * 64 + coff];
        fma8(uA, nA, acc); fma8(uB, nB, acc);
    }
    for (; e + 8 <= e1; e += 8) {
        int s = csrs[e + grp]; float n = csrw[e + grp];
        fma8(S4[(size_t)s * 64 + coff], n, acc);
    }
    if (grp < e1 - e) {                              // tail: rem in [0,8)
        int s = csrs[e + grp]; float n = csrw[e + grp];
        fma8(S4[(size_t)s * 64 + coff], n, acc);
    }
    #pragma unroll
    for (int j = 0; j < 8; ++j) {                    // cross-group reduce (bits 3..5)
        acc[j] += __shfl_xor(acc[j], 8);
        acc[j] += __shfl_xor(acc[j], 16);
        acc[j] += __shfl_xor(acc[j], 32);
    }
    float dw = dis[w];
    float btv[8];
    *(float4*)&btv[0] = *(const float4*)(btot + chunk * 64 + li * 8);
    *(float4*)&btv[4] = *(const float4*)(btot + chunk * 64 + li * 8 + 4);
    float v0[8], x1[8], x2[8], x3[8];
    #pragma unroll
    for (int j = 0; j < 8; ++j) v0[j] = dw * acc[j] + btv[j];
    #pragma unroll
    for (int j = 0; j < 8; ++j) {                    // gather all 4 gates per feat
        x1[j] = __shfl_xor(v0[j], 2);
        x2[j] = __shfl_xor(v0[j], 4);
        x3[j] = __shfl_xor(v0[j], 6);
    }
    if (grp == 0 && li < 2) {                        // gate-0 lanes: 2 x 8 feats
        int hh0 = chunk * 16 + li * 8;
        const float* cp = c + (size_t)w * CH + hh0;
        float hn[8], cn[8];
        #pragma unroll
        for (int j = 0; j < 8; ++j) {
            int hh = hh0 + j;
            float cv = cp[j];
            float I  = 1.f / (1.f + expf(-(v0[j] + wc[hh]       * cv)));
            float F  = 1.f / (1.f + expf(-(x1[j] + wc[128 + hh] * cv)));
            float T  = tanhf(x2[j]);
            float Cn = F * cv + I * T;
            float O  = 1.f / (1.f + expf(-(x3[j] + wc[256 + hh] * Cn)));
            hn[j] = O * tanhf(Cn); cn[j] = Cn;
        }
        float* op  = out + (size_t)w * CH + hh0;
        float* op2 = out + NHtot + (size_t)w * CH + hh0;
        *(float4*)op        = *(float4*)&hn[0];
        *(float4*)(op + 4)  = *(float4*)&hn[4];
        *(float4*)op2       = *(float4*)&cn[0];
        *(float4*)(op2 + 4) = *(float4*)&cn[4];
    }
}

extern "C" void kernel_launch(void* const* d_in, const int* in_sizes, int n_in,
                              void* d_out, int out_size, void* d_ws, size_t ws_size,
                              hipStream_t stream) {
    (void)in_sizes; (void)n_in; (void)out_size; (void)ws_size;
    const float* x   = (const float*)d_in[0];
    const int*   ei  = (const int*)d_in[1];
    const float* ew  = (const float*)d_in[2];
    const float* h   = (const float*)d_in[3];
    const float* c   = (const float*)d_in[4];
    const float* Wx0 = (const float*)d_in[5];
    const float* bx0 = (const float*)d_in[6];
    const float* Wx1 = (const float*)d_in[7];
    const float* bx1 = (const float*)d_in[8];
    const float* Wh0 = (const float*)d_in[9];
    const float* bh0 = (const float*)d_in[10];
    const float* Wh1 = (const float*)d_in[11];
    const float* bh1 = (const float*)d_in[12];
    const float* wc  = (const float*)d_in[13];
    const float* bg  = (const float*)d_in[14];
    float* out = (float*)d_out;

    // Workspace layout (float units) — validated R7/R9/R10/R12 layout.
    float* wsf  = (float*)d_ws;
    float* dis  = wsf;                                  // [20480]
    int*   cnt  = (int*)(wsf + 20480);                  // [20480]  zeroed
    int*   row  = (int*)(wsf + 40960);                  // [20736]
    int*   cur  = (int*)(wsf + 61696);                  // [20480]
    int*   bsum = (int*)(wsf + 82176);                  // [256]
    float* btot = wsf + 82432;                          // [512]
    int*   csrs = (int*)(wsf + 82944);                  // [E]
    float* csrw = wsf + 402944;                         // [E] raw weights
    unsigned short* Wt0x = (unsigned short*)(wsf + 722944);   // +32768 floats each
    unsigned short* Wt0h = (unsigned short*)(wsf + 755712);
    unsigned short* Wt1x = (unsigned short*)(wsf + 788480);
    unsigned short* Wt1h = (unsigned short*)(wsf + 821248);
    unsigned short* xhb  = (unsigned short*)(wsf + 854016);   // [NP*256] bf16
    unsigned short* axh  = (unsigned short*)(wsf + 3426304);  // [NP*256] bf16
    unsigned short* h0x  = (unsigned short*)(wsf + 5998592);  // [NP*512] bf16
    unsigned short* h0h  = (unsigned short*)(wsf + 11143168); // [NP*512] bf16
    unsigned short* Sb   = (unsigned short*)(wsf + 16287744); // [NP*512] bf16

    hipMemsetAsync(cnt, 0, 20480 * sizeof(int), stream);

    k_cntprep<<<EE / 256 + 1024, 256, 0, stream>>>(ei, cnt,
                                                   Wx0, Wh0, Wx1, Wh1,
                                                   Wt0x, Wt0h, Wt1x, Wt1h,
                                                   bx1, bh1, bg, btot);
    k_scan1  <<<80, 256, 0, stream>>>(cnt, row, bsum);
    k_scan2  <<<1, 64, 0, stream>>>(bsum);
    k_scan3  <<<80, 256, 0, stream>>>(row, bsum, cur);
    k_scatter<<<EE / 256, 256, 0, stream>>>(ei, ew, cur, csrs, csrw);

    k_degcast<<<NN / 4, 256, 0, stream>>>(x, h, row, csrw, dis, xhb);

    k_prop256c<<<(NN / 4) * 4, 256, 0, stream>>>(xhb, axh, row, csrs, csrw, dis);

    dim3 g1(NP / 128, 4, 2);
    k_gemm1<<<g1, 256, 0, stream>>>(axh, Wt0x, Wt0h, bx0, bh0, h0x, h0h);
    dim3 g2(NP / 128, 4);
    k_gemm2<<<g2, 256, 0, stream>>>(h0x, h0h, Wt1x, Wt1h, dis, Sb);

    k_prop512v<<<(NN / 4) * 8, 256, 0, stream>>>(Sb, out, row, csrs, csrw, dis, c, btot, wc);
}

// Round 5
// 292.988 us; speedup vs baseline: 1.4677x; 1.4677x over previous
//
#include <hip/hip_runtime.h>
#include <hip/hip_bf16.h>
#include <stdint.h>

// Problem constants (fixed by the reference)
#define NN    20000      // nodes
#define NP    20096      // nodes padded to 157*128 (garbage rows never read back)
#define EE    320000     // edges (w/o self loops)
#define CH    128        // feature width per gate
#define GC    512        // 4 gates * 128
#define NHtot 2560000    // N*CH

typedef short bf16x8 __attribute__((ext_vector_type(8)));   // 8 bf16 (4 VGPRs)
typedef float f32x4  __attribute__((ext_vector_type(4)));   // 4 fp32 acc

// ---------- bf16 helpers ----------
__device__ __forceinline__ unsigned short f2bf(float f) {
    __hip_bfloat16 b = __float2bfloat16(f);           // RNE
    union { __hip_bfloat16 b; unsigned short u; } c; c.b = b; return c.u;
}
// fast bf16x2 dword -> two f32: lo = u<<16, hi = u & 0xffff0000 (1 VALU op each)
__device__ __forceinline__ void fma8(uint4 u, float n, float* acc) {
    union { unsigned int i; float f; } t;
    t.i = u.x << 16;         acc[0] += n * t.f;
    t.i = u.x & 0xffff0000u; acc[1] += n * t.f;
    t.i = u.y << 16;         acc[2] += n * t.f;
    t.i = u.y & 0xffff0000u; acc[3] += n * t.f;
    t.i = u.z << 16;         acc[4] += n * t.f;
    t.i = u.z & 0xffff0000u; acc[5] += n * t.f;
    t.i = u.w << 16;         acc[6] += n * t.f;
    t.i = u.w & 0xffff0000u; acc[7] += n * t.f;
}
__device__ __forceinline__ void tof8(uint4 u, float* f) {
    union { unsigned int i; float f; } t;
    t.i = u.x << 16;         f[0] = t.f;
    t.i = u.x & 0xffff0000u; f[1] = t.f;
    t.i = u.y << 16;         f[2] = t.f;
    t.i = u.y & 0xffff0000u; f[3] = t.f;
    t.i = u.z << 16;         f[4] = t.f;
    t.i = u.z & 0xffff0000u; f[5] = t.f;
    t.i = u.w << 16;         f[6] = t.f;
    t.i = u.w & 0xffff0000u; f[7] = t.f;
}
__device__ __forceinline__ uint2 pack4(const float* f) {
    uint2 v;
    v.x = (unsigned int)f2bf(f[0]) | ((unsigned int)f2bf(f[1]) << 16);
    v.y = (unsigned int)f2bf(f[2]) | ((unsigned int)f2bf(f[3]) << 16);
    return v;
}
// async 16B global -> LDS (lane deposits at lds_base + lane*16)
__device__ __forceinline__ void gload_lds16(const void* g, void* l) {
    __builtin_amdgcn_global_load_lds(
        (const __attribute__((address_space(1))) void*)g,
        (__attribute__((address_space(3))) void*)l, 16, 0, 0);
}

// ---------- 1. MERGED: edge count (int atomics) + weight prep + btot ----------
// blocks [0,1250): count; blocks [1250,2274): transpose/cast weights (+btot).
// btot is PLAIN layout [4][128] (consumed by k_lstm, not by prop).
__global__ void k_cntprep(const int* __restrict__ ei, int* __restrict__ cnt,
                          const float* __restrict__ W0, const float* __restrict__ W1,
                          const float* __restrict__ W2, const float* __restrict__ W3,
                          unsigned short* __restrict__ T0, unsigned short* __restrict__ T1,
                          unsigned short* __restrict__ T2, unsigned short* __restrict__ T3,
                          const float* __restrict__ bx1, const float* __restrict__ bh1,
                          const float* __restrict__ bg, float* __restrict__ btot) {
    int bid = blockIdx.x;
    if (bid < EE / 256) {
        int e = bid * 256 + threadIdx.x;
        atomicAdd(&cnt[ei[EE + e]], 1);
        return;
    }
    int pid = bid - EE / 256;                        // 0..1023
    int z = pid >> 8, y = (pid >> 6) & 3, xb = pid & 63;
    if (z == 0 && y == 0 && xb < 2) {
        int f = xb * 256 + threadIdx.x;              // 512 entries, f = g*128+hh
        btot[f] = bx1[f] + bh1[f] + bg[f];
    }
    const float* W; unsigned short* T;
    switch (z) {
        case 0:  W = W0; T = T0; break;
        case 1:  W = W1; T = T1; break;
        case 2:  W = W2; T = T2; break;
        default: W = W3; T = T3; break;
    }
    int n = xb * 2 + (threadIdx.x >> 7);
    int k = threadIdx.x & 127;
    T[((size_t)y * 128 + n) * 128 + k] = f2bf(W[((size_t)y * 128 + k) * 128 + n]);
}

// ---------- 2. hierarchical exclusive scan of counts ----------
__global__ void k_scan1(const int* __restrict__ cnt, int* __restrict__ rowoff,
                        int* __restrict__ bsum) {
    __shared__ int wsum[4];
    int i = blockIdx.x * 256 + threadIdx.x;
    int self = (i < NN) ? cnt[i] : 0;
    int lane = threadIdx.x & 63, wid = threadIdx.x >> 6;
    int v = self;
    #pragma unroll
    for (int off = 1; off < 64; off <<= 1) {
        int u = __shfl_up(v, off);
        if (lane >= off) v += u;
    }
    if (lane == 63) wsum[wid] = v;
    __syncthreads();
    int wof = 0;
    for (int k = 0; k < wid; ++k) wof += wsum[k];
    if (i < NN) rowoff[i] = wof + v - self;
    if (threadIdx.x == 255) bsum[blockIdx.x] = wof + v;
}

__global__ void k_scan2(int* __restrict__ bsum) {
    int lane = threadIdx.x;                          // 64 threads
    int base = 0;
    for (int start = 0; start < 80; start += 64) {
        int i = start + lane;
        int self = (i < 80) ? bsum[i] : 0;
        int v = self;
        #pragma unroll
        for (int off = 1; off < 64; off <<= 1) {
            int u = __shfl_up(v, off);
            if (lane >= off) v += u;
        }
        if (i < 80) bsum[i] = base + v - self;
        base += __shfl(v, 63);
    }
}

__global__ void k_scan3(int* __restrict__ rowoff, const int* __restrict__ bsum,
                        int* __restrict__ cur) {
    int i = blockIdx.x * 256 + threadIdx.x;
    if (i < NN) {
        int v = rowoff[i] + bsum[i >> 8];
        rowoff[i] = v; cur[i] = v;
    }
    if (i == NN) rowoff[NN] = EE;
}

// ---------- 3. scatter edges into CSR with RAW weights ----------
__global__ void k_scatter(const int* __restrict__ ei, const float* __restrict__ ew,
                          int* __restrict__ cur,
                          int* __restrict__ csrs, float* __restrict__ csrw) {
    int e = blockIdx.x * 256 + threadIdx.x;
    if (e >= EE) return;
    int s = ei[e], d = ei[EE + e];
    int p = atomicAdd(&cur[d], 1);
    csrs[p] = s; csrw[p] = ew[e];
}

// ---------- 4. FUSED: degree row-sum -> dis -> scale & pack x|h to bf16 ----------
__global__ __launch_bounds__(256) void k_degcast(
        const float* __restrict__ x, const float* __restrict__ h,
        const int* __restrict__ rowoff, const float* __restrict__ csrw,
        float* __restrict__ dis, unsigned short* __restrict__ xhb) {
    int wid = threadIdx.x >> 6, lane = threadIdx.x & 63;
    int w = blockIdx.x * 4 + wid;                    // grid exact: NN/4
    int e0 = rowoff[w], e1 = rowoff[w + 1];
    float s = 0.f;
    for (int e = e0 + lane; e < e1; e += 64) s += csrw[e];
    #pragma unroll
    for (int off = 32; off; off >>= 1) s += __shfl_xor(s, off);
    float dn = rsqrtf(fmaxf(1.0f + s, 1e-12f));      // self-loop weight 1
    if (lane == 0) dis[w] = dn;
    const float* src = (lane < 32) ? x + (size_t)w * CH + lane * 4
                                   : h + (size_t)w * CH + (lane - 32) * 4;
    float4 v = *(const float4*)src;
    float f[4] = { dn * v.x, dn * v.y, dn * v.z, dn * v.w };
    *(uint2*)(xhb + (size_t)w * 256 + lane * 4) = pack4(f);
}

// ---------- 5. XCD-chunked prop over 256-wide bf16 rows (table pre-scaled) ----------
// chunk = bid&3 (4 chunks x 128 B slice of each 512 B row). Per-XCD gather
// footprint = NP*128B = 2.57 MB (L2-fit). Wave = 1 node: 8 lane-groups x 8
// lanes x uint4 gather 8 EDGES per load instr.
__global__ __launch_bounds__(256) void k_prop256c(
        const unsigned short* __restrict__ tab, unsigned short* __restrict__ o,
        const int* __restrict__ rowoff, const int* __restrict__ csrs,
        const float* __restrict__ csrw, const float* __restrict__ dis) {
    int chunk = blockIdx.x & 3;
    int w = (blockIdx.x >> 2) * 4 + (threadIdx.x >> 6);   // grid exact: (NN/4)*4
    int l = threadIdx.x & 63, grp = l >> 3, li = l & 7;
    const uint4* T4 = (const uint4*)tab;             // row = 32 uint4 = 512 B
    int coff = chunk * 8 + li;                       // uint4 offset within row
    float acc[8];
    #pragma unroll
    for (int j = 0; j < 8; ++j) acc[j] = 0.f;
    if (grp == 0) tof8(T4[(size_t)w * 32 + coff], acc);   // self term once
    int e = rowoff[w], e1 = rowoff[w + 1];
    for (; e + 16 <= e1; e += 16) {                  // 2 x 8-edge batches in flight
        int   sA = csrs[e + grp],  sB = csrs[e + 8 + grp];
        float nA = csrw[e + grp],  nB = csrw[e + 8 + grp];
        uint4 uA = T4[(size_t)sA * 32 + coff];
        uint4 uB = T4[(size_t)sB * 32 + coff];
        fma8(uA, nA, acc); fma8(uB, nB, acc);
    }
    for (; e + 8 <= e1; e += 8) {
        int s = csrs[e + grp]; float n = csrw[e + grp];
        fma8(T4[(size_t)s * 32 + coff], n, acc);
    }
    if (grp < e1 - e) {                              // tail: rem in [0,8)
        int s = csrs[e + grp]; float n = csrw[e + grp];
        fma8(T4[(size_t)s * 32 + coff], n, acc);
    }
    #pragma unroll
    for (int j = 0; j < 8; ++j) {                    // cross-group reduce (bits 3..5)
        acc[j] += __shfl_xor(acc[j], 8);
        acc[j] += __shfl_xor(acc[j], 16);
        acc[j] += __shfl_xor(acc[j], 32);
    }
    if (grp == 0) {
        float dw = dis[w];
        #pragma unroll
        for (int j = 0; j < 8; ++j) acc[j] *= dw;
        uint2 p0 = pack4(acc), p1 = pack4(acc + 4);
        uint4 ov; ov.x = p0.x; ov.y = p0.y; ov.z = p1.x; ov.w = p1.y;
        ((uint4*)o)[(size_t)w * 32 + coff] = ov;     // linear layout (gemm1 input)
    }
}

// ---------- MFMA GEMM shared machinery ----------
#define SWZ(r, c8) (((r) << 4) + ((c8) ^ ((r) & 15)))

// ---------- 6. GEMM1 (both sides in one launch via blockIdx.z) ----------
// h0 = relu(axh[:, side] @ W0[g] + b0[g]) -> bf16 [NP,512]
__global__ __launch_bounds__(256) void k_gemm1(
        const unsigned short* __restrict__ A,
        const unsigned short* __restrict__ Wtx, const unsigned short* __restrict__ Wth,
        const float* __restrict__ bx0, const float* __restrict__ bh0,
        unsigned short* __restrict__ outx, unsigned short* __restrict__ outh) {
    __shared__ uint4 As[2048];                       // 32 KB
    __shared__ uint4 Bs[2048];                       // 32 KB
    const int side = blockIdx.z;
    const int aoff = side * 128;
    const unsigned short* Wt = side ? Wth : Wtx;
    const float* bias        = side ? bh0 : bx0;
    unsigned short* out      = side ? outh : outx;

    const int    g    = blockIdx.y;
    const size_t row0 = (size_t)blockIdx.x * 128;
    const int    t    = threadIdx.x;
    const int    wv   = t >> 6;                      // wave id (LDS base uniform)
    const unsigned short* Wg = Wt + (size_t)g * 16384;   // [n][k] bf16

    #pragma unroll
    for (int p = 0; p < 8; ++p) {                    // async stage A and W tiles
        int id = t + 256 * p, r = id >> 4, cc = id & 15;
        int c8 = cc ^ (r & 15);                      // XOR swizzle on global side
        gload_lds16(A + (row0 + r) * 256 + aoff + c8 * 8, &As[p * 256 + wv * 64]);
        gload_lds16(Wg + r * CH + c8 * 8,                 &Bs[p * 256 + wv * 64]);
    }
    __syncthreads();                                 // vmcnt(0) drain at barrier

    const int l = t & 63;
    const int m0 = (wv >> 1) * 64, n0 = (wv & 1) * 64;
    const int lm = l & 15, q = l >> 4;
    f32x4 acc[4][4];
    #pragma unroll
    for (int i = 0; i < 4; ++i)
        #pragma unroll
        for (int j = 0; j < 4; ++j) { acc[i][j][0]=0.f; acc[i][j][1]=0.f; acc[i][j][2]=0.f; acc[i][j][3]=0.f; }

    #pragma unroll
    for (int kc = 0; kc < 4; ++kc) {
        int c8 = kc * 4 + q;
        bf16x8 a[4], b[4];
        #pragma unroll
        for (int i = 0; i < 4; ++i) { int r = m0 + i * 16 + lm; a[i] = *(const bf16x8*)&As[SWZ(r, c8)]; }
        #pragma unroll
        for (int j = 0; j < 4; ++j) { int r = n0 + j * 16 + lm; b[j] = *(const bf16x8*)&Bs[SWZ(r, c8)]; }
        #pragma unroll
        for (int i = 0; i < 4; ++i)
            #pragma unroll
            for (int j = 0; j < 4; ++j)
                acc[i][j] = __builtin_amdgcn_mfma_f32_16x16x32_bf16(a[i], b[j], acc[i][j], 0, 0, 0);
    }

    #pragma unroll
    for (int j = 0; j < 4; ++j) {
        float bb = bias[g * CH + n0 + j * 16 + lm];
        #pragma unroll
        for (int i = 0; i < 4; ++i)
            #pragma unroll
            for (int r = 0; r < 4; ++r) {
                int rowl = m0 + i * 16 + q * 4 + r;   // C/D: row=(lane>>4)*4+reg
                int col  = n0 + j * 16 + lm;          //      col=lane&15
                out[(row0 + rowl) * GC + g * CH + col] = f2bf(fmaxf(acc[i][j][r] + bb, 0.f));
            }
    }
}

// ---------- 7. GEMM2 (fused): Sb = dis .* (h0x@Wx1 + h0h@Wh1) -> bf16 [NP,512] ----------
// OUTPUT LAYOUT (for XCD-chunked prop): col = (hh>>4)*64 + g*16 + (hh&15)
__global__ __launch_bounds__(256) void k_gemm2(
        const unsigned short* __restrict__ A1, const unsigned short* __restrict__ A2,
        const unsigned short* __restrict__ Wt1, const unsigned short* __restrict__ Wt2,
        const float* __restrict__ dis, unsigned short* __restrict__ outS) {
    __shared__ uint4 As[2048];
    __shared__ uint4 Bs[2048];
    const int    g    = blockIdx.y;
    const size_t row0 = (size_t)blockIdx.x * 128;
    const int    t    = threadIdx.x;
    const int    wv   = t >> 6;
    const int l = t & 63;
    const int m0 = (wv >> 1) * 64, n0 = (wv & 1) * 64;
    const int lm = l & 15, q = l >> 4;
    f32x4 acc[4][4];
    #pragma unroll
    for (int i = 0; i < 4; ++i)
        #pragma unroll
        for (int j = 0; j < 4; ++j) { acc[i][j][0]=0.f; acc[i][j][1]=0.f; acc[i][j][2]=0.f; acc[i][j][3]=0.f; }

    for (int side = 0; side < 2; ++side) {
        if (side) __syncthreads();                   // all waves done reading LDS
        const unsigned short* Ap = side ? A2 : A1;
        const unsigned short* Wg = (side ? Wt2 : Wt1) + (size_t)g * 16384;
        #pragma unroll
        for (int p = 0; p < 8; ++p) {                // async stage A and W tiles
            int id = t + 256 * p, r = id >> 4, cc = id & 15;
            int c8 = cc ^ (r & 15);
            gload_lds16(Ap + (row0 + r) * GC + g * CH + c8 * 8, &As[p * 256 + wv * 64]);
            gload_lds16(Wg + r * CH + c8 * 8,                   &Bs[p * 256 + wv * 64]);
        }
        __syncthreads();
        #pragma unroll
        for (int kc = 0; kc < 4; ++kc) {
            int c8 = kc * 4 + q;
            bf16x8 a[4], b[4];
            #pragma unroll
            for (int i = 0; i < 4; ++i) { int r = m0 + i * 16 + lm; a[i] = *(const bf16x8*)&As[SWZ(r, c8)]; }
            #pragma unroll
            for (int j = 0; j < 4; ++j) { int r = n0 + j * 16 + lm; b[j] = *(const bf16x8*)&Bs[SWZ(r, c8)]; }
            #pragma unroll
            for (int i = 0; i < 4; ++i)
                #pragma unroll
                for (int j = 0; j < 4; ++j)
                    acc[i][j] = __builtin_amdgcn_mfma_f32_16x16x32_bf16(a[i], b[j], acc[i][j], 0, 0, 0);
        }
    }

    #pragma unroll
    for (int j = 0; j < 4; ++j) {
        int fh = (n0 + j * 16) >> 4;                 // feature-group (in-gate col / 16)
        #pragma unroll
        for (int i = 0; i < 4; ++i)
            #pragma unroll
            for (int r = 0; r < 4; ++r) {
                int rowl = m0 + i * 16 + q * 4 + r;
                float dr = dis[row0 + rowl];         // pre-scale for prop
                outS[(row0 + rowl) * GC + fh * 64 + g * 16 + lm] = f2bf(dr * acc[i][j][r]);
            }
    }
}

// ---------- 8. XCD-chunked prop over interleaved Sb -> fp32 Gbuf (NO LSTM) ----------
// chunk = bid&7 == XCD; per-XCD gather footprint = NP*128B = 2.57 MB (L2-fit).
// Wave = 1 node: 8 lane-groups x 8 lanes x uint4 -> 8 EDGES per gather instr.
// Tail: cross-group reduce, scale by dis, store fp32 to Gbuf (same interleaved
// cols). LSTM moved to k_lstm (round-4 lesson: 8-feat-serial transcendental
// unroll per wave was ~1000 instrs -> 3.4x VALU-cycle blowup).
__global__ __launch_bounds__(256) void k_prop512w(
        const unsigned short* __restrict__ Sb, float* __restrict__ Gbuf,
        const int* __restrict__ rowoff, const int* __restrict__ csrs,
        const float* __restrict__ csrw, const float* __restrict__ dis) {
    int chunk = blockIdx.x & 7;
    int w = (blockIdx.x >> 3) * 4 + (threadIdx.x >> 6);   // grid exact: (NN/4)*8
    int l = threadIdx.x & 63, grp = l >> 3, li = l & 7;
    const uint4* S4 = (const uint4*)Sb;              // row = 64 uint4 = 1 KB
    int coff = chunk * 8 + li;                       // uint4 offset within row
    float acc[8];
    #pragma unroll
    for (int j = 0; j < 8; ++j) acc[j] = 0.f;
    if (grp == 0) tof8(S4[(size_t)w * 64 + coff], acc);   // self term once
    int e = rowoff[w], e1 = rowoff[w + 1];
    for (; e + 16 <= e1; e += 16) {                  // 2 x 8-edge batches in flight
        int   sA = csrs[e + grp],  sB = csrs[e + 8 + grp];
        float nA = csrw[e + grp],  nB = csrw[e + 8 + grp];
        uint4 uA = S4[(size_t)sA * 64 + coff];
        uint4 uB = S4[(size_t)sB * 64 + coff];
        fma8(uA, nA, acc); fma8(uB, nB, acc);
    }
    for (; e + 8 <= e1; e += 8) {
        int s = csrs[e + grp]; float n = csrw[e + grp];
        fma8(S4[(size_t)s * 64 + coff], n, acc);
    }
    if (grp < e1 - e) {                              // tail: rem in [0,8)
        int s = csrs[e + grp]; float n = csrw[e + grp];
        fma8(S4[(size_t)s * 64 + coff], n, acc);
    }
    #pragma unroll
    for (int j = 0; j < 8; ++j) {                    // cross-group reduce (bits 3..5)
        acc[j] += __shfl_xor(acc[j], 8);
        acc[j] += __shfl_xor(acc[j], 16);
        acc[j] += __shfl_xor(acc[j], 32);
    }
    if (grp == 0) {                                  // 8 lanes x 32B = 256B/wave
        float dw = dis[w];
        #pragma unroll
        for (int j = 0; j < 8; ++j) acc[j] *= dw;
        float* gp = Gbuf + (size_t)w * GC + chunk * 64 + li * 8;
        *(float4*)gp       = *(float4*)&acc[0];
        *(float4*)(gp + 4) = *(float4*)&acc[4];
    }
}

// ---------- 9. LSTM gate kernel: 1 thread per (node, feature) ----------
// Reads interleaved Gbuf: col(hh,g) = (hh>>4)*64 + g*16 + (hh&15).
// All transcendentals fully lane-parallel (no serial unroll, no replication).
__global__ __launch_bounds__(256) void k_lstm(
        const float* __restrict__ Gbuf, const float* __restrict__ c,
        const float* __restrict__ btot, const float* __restrict__ wc,
        float* __restrict__ out) {
    int t = threadIdx.x;
    int w = blockIdx.x * 2 + (t >> 7);               // grid exact: NN/2
    int hh = t & 127;
    const float* gr = Gbuf + (size_t)w * GC + ((hh >> 4) << 6) + (hh & 15);
    float g0 = gr[0]  + btot[hh];
    float g1 = gr[16] + btot[128 + hh];
    float g2 = gr[32] + btot[256 + hh];
    float g3 = gr[48] + btot[384 + hh];
    float cv = c[(size_t)w * CH + hh];
    float I  = 1.f / (1.f + expf(-(g0 + wc[hh]       * cv)));
    float F  = 1.f / (1.f + expf(-(g1 + wc[128 + hh] * cv)));
    float T  = tanhf(g2);
    float Cn = F * cv + I * T;
    float O  = 1.f / (1.f + expf(-(g3 + wc[256 + hh] * Cn)));
    out[(size_t)w * CH + hh]         = O * tanhf(Cn);   // Hn
    out[NHtot + (size_t)w * CH + hh] = Cn;              // Cn
}

extern "C" void kernel_launch(void* const* d_in, const int* in_sizes, int n_in,
                              void* d_out, int out_size, void* d_ws, size_t ws_size,
                              hipStream_t stream) {
    (void)in_sizes; (void)n_in; (void)out_size; (void)ws_size;
    const float* x   = (const float*)d_in[0];
    const int*   ei  = (const int*)d_in[1];
    const float* ew  = (const float*)d_in[2];
    const float* h   = (const float*)d_in[3];
    const float* c   = (const float*)d_in[4];
    const float* Wx0 = (const float*)d_in[5];
    const float* bx0 = (const float*)d_in[6];
    const float* Wx1 = (const float*)d_in[7];
    const float* bx1 = (const float*)d_in[8];
    const float* Wh0 = (const float*)d_in[9];
    const float* bh0 = (const float*)d_in[10];
    const float* Wh1 = (const float*)d_in[11];
    const float* bh1 = (const float*)d_in[12];
    const float* wc  = (const float*)d_in[13];
    const float* bg  = (const float*)d_in[14];
    float* out = (float*)d_out;

    // Workspace layout (float units).
    float* wsf  = (float*)d_ws;
    float* dis  = wsf;                                  // [20480]
    int*   cnt  = (int*)(wsf + 20480);                  // [20480]  zeroed
    int*   row  = (int*)(wsf + 40960);                  // [20736]
    int*   cur  = (int*)(wsf + 61696);                  // [20480]
    int*   bsum = (int*)(wsf + 82176);                  // [256]
    float* btot = wsf + 82432;                          // [512]
    int*   csrs = (int*)(wsf + 82944);                  // [E]
    float* csrw = wsf + 402944;                         // [E] raw weights
    unsigned short* Wt0x = (unsigned short*)(wsf + 722944);   // +32768 floats each
    unsigned short* Wt0h = (unsigned short*)(wsf + 755712);
    unsigned short* Wt1x = (unsigned short*)(wsf + 788480);
    unsigned short* Wt1h = (unsigned short*)(wsf + 821248);
    unsigned short* xhb  = (unsigned short*)(wsf + 854016);   // [NP*256] bf16
    unsigned short* axh  = (unsigned short*)(wsf + 3426304);  // [NP*256] bf16
    unsigned short* h0x  = (unsigned short*)(wsf + 5998592);  // [NP*512] bf16
    unsigned short* h0h  = (unsigned short*)(wsf + 11143168); // [NP*512] bf16
    unsigned short* Sb   = (unsigned short*)(wsf + 16287744); // [NP*512] bf16
    // Gbuf fp32 [NP*512] REUSES the h0x+h0h region (dead after k_gemm2):
    // 5998592 + NP*512 = 16287744 exactly -> no overlap with Sb.
    float* Gbuf = wsf + 5998592;

    hipMemsetAsync(cnt, 0, 20480 * sizeof(int), stream);

    k_cntprep<<<EE / 256 + 1024, 256, 0, stream>>>(ei, cnt,
                                                   Wx0, Wh0, Wx1, Wh1,
                                                   Wt0x, Wt0h, Wt1x, Wt1h,
                                                   bx1, bh1, bg, btot);
    k_scan1  <<<80, 256, 0, stream>>>(cnt, row, bsum);
    k_scan2  <<<1, 64, 0, stream>>>(bsum);
    k_scan3  <<<80, 256, 0, stream>>>(row, bsum, cur);
    k_scatter<<<EE / 256, 256, 0, stream>>>(ei, ew, cur, csrs, csrw);

    k_degcast<<<NN / 4, 256, 0, stream>>>(x, h, row, csrw, dis, xhb);

    k_prop256c<<<(NN / 4) * 4, 256, 0, stream>>>(xhb, axh, row, csrs, csrw, dis);

    dim3 g1(NP / 128, 4, 2);
    k_gemm1<<<g1, 256, 0, stream>>>(axh, Wt0x, Wt0h, bx0, bh0, h0x, h0h);
    dim3 g2(NP / 128, 4);
    k_gemm2<<<g2, 256, 0, stream>>>(h0x, h0h, Wt1x, Wt1h, dis, Sb);

    k_prop512w<<<(NN / 4) * 8, 256, 0, stream>>>(Sb, Gbuf, row, csrs, csrw, dis);
    k_lstm<<<NN / 2, 256, 0, stream>>>(Gbuf, c, btot, wc, out);
}

// Round 6
// 259.021 us; speedup vs baseline: 1.6601x; 1.1311x over previous
//
#include <hip/hip_runtime.h>
#include <hip/hip_bf16.h>
#include <stdint.h>

// Problem constants (fixed by the reference)
#define NN    20000      // nodes
#define NP    20096      // nodes padded to 157*128 (garbage rows never read back)
#define EE    320000     // edges (w/o self loops)
#define CH    128        // feature width per gate
#define GC    512        // 4 gates * 128
#define NHtot 2560000    // N*CH

typedef short bf16x8 __attribute__((ext_vector_type(8)));   // 8 bf16 (4 VGPRs)
typedef float f32x4  __attribute__((ext_vector_type(4)));   // 4 fp32 acc

// ---------- bf16 helpers ----------
__device__ __forceinline__ unsigned short f2bf(float f) {
    __hip_bfloat16 b = __float2bfloat16(f);           // RNE
    union { __hip_bfloat16 b; unsigned short u; } c; c.b = b; return c.u;
}
// fast bf16x2 dword -> two f32: lo = u<<16, hi = u & 0xffff0000 (1 VALU op each)
__device__ __forceinline__ void fma8(uint4 u, float n, float* acc) {
    union { unsigned int i; float f; } t;
    t.i = u.x << 16;         acc[0] += n * t.f;
    t.i = u.x & 0xffff0000u; acc[1] += n * t.f;
    t.i = u.y << 16;         acc[2] += n * t.f;
    t.i = u.y & 0xffff0000u; acc[3] += n * t.f;
    t.i = u.z << 16;         acc[4] += n * t.f;
    t.i = u.z & 0xffff0000u; acc[5] += n * t.f;
    t.i = u.w << 16;         acc[6] += n * t.f;
    t.i = u.w & 0xffff0000u; acc[7] += n * t.f;
}
__device__ __forceinline__ void tof8(uint4 u, float* f) {
    union { unsigned int i; float f; } t;
    t.i = u.x << 16;         f[0] = t.f;
    t.i = u.x & 0xffff0000u; f[1] = t.f;
    t.i = u.y << 16;         f[2] = t.f;
    t.i = u.y & 0xffff0000u; f[3] = t.f;
    t.i = u.z << 16;         f[4] = t.f;
    t.i = u.z & 0xffff0000u; f[5] = t.f;
    t.i = u.w << 16;         f[6] = t.f;
    t.i = u.w & 0xffff0000u; f[7] = t.f;
}
__device__ __forceinline__ uint2 pack4(const float* f) {
    uint2 v;
    v.x = (unsigned int)f2bf(f[0]) | ((unsigned int)f2bf(f[1]) << 16);
    v.y = (unsigned int)f2bf(f[2]) | ((unsigned int)f2bf(f[3]) << 16);
    return v;
}
__device__ __forceinline__ uint4 pack8(const float* f) {
    uint4 v;
    v.x = (unsigned int)f2bf(f[0]) | ((unsigned int)f2bf(f[1]) << 16);
    v.y = (unsigned int)f2bf(f[2]) | ((unsigned int)f2bf(f[3]) << 16);
    v.z = (unsigned int)f2bf(f[4]) | ((unsigned int)f2bf(f[5]) << 16);
    v.w = (unsigned int)f2bf(f[6]) | ((unsigned int)f2bf(f[7]) << 16);
    return v;
}
// async 16B global -> LDS (lane deposits at lds_base + lane*16)
__device__ __forceinline__ void gload_lds16(const void* g, void* l) {
    __builtin_amdgcn_global_load_lds(
        (const __attribute__((address_space(1))) void*)g,
        (__attribute__((address_space(3))) void*)l, 16, 0, 0);
}

// ---------- 1. MERGED: edge count (int atomics) + weight prep + btot ----------
__global__ void k_cntprep(const int* __restrict__ ei, int* __restrict__ cnt,
                          const float* __restrict__ W0, const float* __restrict__ W1,
                          const float* __restrict__ W2, const float* __restrict__ W3,
                          unsigned short* __restrict__ T0, unsigned short* __restrict__ T1,
                          unsigned short* __restrict__ T2, unsigned short* __restrict__ T3,
                          const float* __restrict__ bx1, const float* __restrict__ bh1,
                          const float* __restrict__ bg, float* __restrict__ btot) {
    int bid = blockIdx.x;
    if (bid < EE / 256) {
        int e = bid * 256 + threadIdx.x;
        atomicAdd(&cnt[ei[EE + e]], 1);
        return;
    }
    int pid = bid - EE / 256;                        // 0..1023
    int z = pid >> 8, y = (pid >> 6) & 3, xb = pid & 63;
    if (z == 0 && y == 0 && xb < 2) {
        int f = xb * 256 + threadIdx.x;              // 512 entries, f = g*128+hh
        btot[f] = bx1[f] + bh1[f] + bg[f];
    }
    const float* W; unsigned short* T;
    switch (z) {
        case 0:  W = W0; T = T0; break;
        case 1:  W = W1; T = T1; break;
        case 2:  W = W2; T = T2; break;
        default: W = W3; T = T3; break;
    }
    int n = xb * 2 + (threadIdx.x >> 7);
    int k = threadIdx.x & 127;
    T[((size_t)y * 128 + n) * 128 + k] = f2bf(W[((size_t)y * 128 + k) * 128 + n]);
}

// ---------- 2. hierarchical exclusive scan of counts ----------
__global__ void k_scan1(const int* __restrict__ cnt, int* __restrict__ rowoff,
                        int* __restrict__ bsum) {
    __shared__ int wsum[4];
    int i = blockIdx.x * 256 + threadIdx.x;
    int self = (i < NN) ? cnt[i] : 0;
    int lane = threadIdx.x & 63, wid = threadIdx.x >> 6;
    int v = self;
    #pragma unroll
    for (int off = 1; off < 64; off <<= 1) {
        int u = __shfl_up(v, off);
        if (lane >= off) v += u;
    }
    if (lane == 63) wsum[wid] = v;
    __syncthreads();
    int wof = 0;
    for (int k = 0; k < wid; ++k) wof += wsum[k];
    if (i < NN) rowoff[i] = wof + v - self;
    if (threadIdx.x == 255) bsum[blockIdx.x] = wof + v;
}

__global__ void k_scan2(int* __restrict__ bsum) {
    int lane = threadIdx.x;                          // 64 threads
    int base = 0;
    for (int start = 0; start < 80; start += 64) {
        int i = start + lane;
        int self = (i < 80) ? bsum[i] : 0;
        int v = self;
        #pragma unroll
        for (int off = 1; off < 64; off <<= 1) {
            int u = __shfl_up(v, off);
            if (lane >= off) v += u;
        }
        if (i < 80) bsum[i] = base + v - self;
        base += __shfl(v, 63);
    }
}

__global__ void k_scan3(int* __restrict__ rowoff, const int* __restrict__ bsum,
                        int* __restrict__ cur) {
    int i = blockIdx.x * 256 + threadIdx.x;
    if (i < NN) {
        int v = rowoff[i] + bsum[i >> 8];
        rowoff[i] = v; cur[i] = v;
    }
    if (i == NN) rowoff[NN] = EE;
}

// ---------- 3. scatter edges into CSR with RAW weights ----------
__global__ void k_scatter(const int* __restrict__ ei, const float* __restrict__ ew,
                          int* __restrict__ cur,
                          int* __restrict__ csrs, float* __restrict__ csrw) {
    int e = blockIdx.x * 256 + threadIdx.x;
    if (e >= EE) return;
    int s = ei[e], d = ei[EE + e];
    int p = atomicAdd(&cur[d], 1);
    csrs[p] = s; csrw[p] = ew[e];
}

// ---------- 4. FUSED: degree row-sum -> dis -> scale & pack x|h to bf16 ----------
__global__ __launch_bounds__(256) void k_degcast(
        const float* __restrict__ x, const float* __restrict__ h,
        const int* __restrict__ rowoff, const float* __restrict__ csrw,
        float* __restrict__ dis, unsigned short* __restrict__ xhb) {
    int wid = threadIdx.x >> 6, lane = threadIdx.x & 63;
    int w = blockIdx.x * 4 + wid;                    // grid exact: NN/4
    int e0 = rowoff[w], e1 = rowoff[w + 1];
    float s = 0.f;
    for (int e = e0 + lane; e < e1; e += 64) s += csrw[e];
    #pragma unroll
    for (int off = 32; off; off >>= 1) s += __shfl_xor(s, off);
    float dn = rsqrtf(fmaxf(1.0f + s, 1e-12f));      // self-loop weight 1
    if (lane == 0) dis[w] = dn;
    const float* src = (lane < 32) ? x + (size_t)w * CH + lane * 4
                                   : h + (size_t)w * CH + (lane - 32) * 4;
    float4 v = *(const float4*)src;
    float f[4] = { dn * v.x, dn * v.y, dn * v.z, dn * v.w };
    *(uint2*)(xhb + (size_t)w * 256 + lane * 4) = pack4(f);
}

// ---------- 5. XCD-chunked prop, 8 NODES/WAVE, serial edges, NO reduce ----------
// chunk = bid&3 (128 B slice of the 512 B row) -> per-XCD footprint 2.57 MB.
// Wave = 8 nodes x 8 lanes; lane owns (node grp, 16B slice li) and privately
// accumulates its 8 features over the node's edge list (round-0's reduce-free
// property + round-5's L2 chunk residency). Loop = wave-max degree, branch-free
// predication: inactive lanes gather csrs[0]'s row with weight 0 (1 shared
// extra line/instr). R5 lesson: 1-node/wave paid ~100-instr overhead + 48-op
// reduce per deg~16 edge loop.
__global__ __launch_bounds__(256) void k_prop256m(
        const unsigned short* __restrict__ tab, unsigned short* __restrict__ o,
        const int* __restrict__ rowoff, const int* __restrict__ csrs,
        const float* __restrict__ csrw, const float* __restrict__ dis) {
    int chunk = blockIdx.x & 3;
    int wbase = (blockIdx.x >> 2) * 32 + (threadIdx.x >> 6) * 8;  // grid: (NN/32)*4
    int l = threadIdx.x & 63, grp = l >> 3, li = l & 7;
    int w = wbase + grp;
    const uint4* T4 = (const uint4*)tab;             // row = 32 uint4 = 512 B
    int coff = chunk * 8 + li;
    float acc[8];
    tof8(T4[(size_t)w * 32 + coff], acc);            // self term (every lane)
    int e0 = rowoff[w], deg = rowoff[w + 1] - e0;
    int md = deg;                                    // wave-max degree (bits 3..5)
    md = max(md, __shfl_xor(md, 8));
    md = max(md, __shfl_xor(md, 16));
    md = max(md, __shfl_xor(md, 32));
    int k = 0;
    for (; k + 2 <= md; k += 2) {
        bool a0 = k < deg, a1 = k + 1 < deg;
        int i0 = a0 ? e0 + k : 0, i1 = a1 ? e0 + k + 1 : 0;
        int s0 = csrs[i0], s1 = csrs[i1];
        float n0 = a0 ? csrw[i0] : 0.f;
        float n1 = a1 ? csrw[i1] : 0.f;
        uint4 u0 = T4[(size_t)s0 * 32 + coff];
        uint4 u1 = T4[(size_t)s1 * 32 + coff];
        fma8(u0, n0, acc); fma8(u1, n1, acc);
    }
    if (k < md) {
        bool a = k < deg;
        int i0 = a ? e0 + k : 0;
        int s = csrs[i0]; float n = a ? csrw[i0] : 0.f;
        fma8(T4[(size_t)s * 32 + coff], n, acc);
    }
    float dw = dis[w];
    #pragma unroll
    for (int j = 0; j < 8; ++j) acc[j] *= dw;
    ((uint4*)o)[(size_t)w * 32 + coff] = pack8(acc); // linear layout (gemm1 input)
}

// ---------- MFMA GEMM shared machinery ----------
#define SWZ(r, c8) (((r) << 4) + ((c8) ^ ((r) & 15)))

// ---------- 6. GEMM1 (both sides in one launch via blockIdx.z) ----------
// h0 = relu(axh[:, side] @ W0[g] + b0[g]) -> bf16 [NP,512]
__global__ __launch_bounds__(256) void k_gemm1(
        const unsigned short* __restrict__ A,
        const unsigned short* __restrict__ Wtx, const unsigned short* __restrict__ Wth,
        const float* __restrict__ bx0, const float* __restrict__ bh0,
        unsigned short* __restrict__ outx, unsigned short* __restrict__ outh) {
    __shared__ uint4 As[2048];                       // 32 KB
    __shared__ uint4 Bs[2048];                       // 32 KB
    const int side = blockIdx.z;
    const int aoff = side * 128;
    const unsigned short* Wt = side ? Wth : Wtx;
    const float* bias        = side ? bh0 : bx0;
    unsigned short* out      = side ? outh : outx;

    const int    g    = blockIdx.y;
    const size_t row0 = (size_t)blockIdx.x * 128;
    const int    t    = threadIdx.x;
    const int    wv   = t >> 6;                      // wave id (LDS base uniform)
    const unsigned short* Wg = Wt + (size_t)g * 16384;   // [n][k] bf16

    #pragma unroll
    for (int p = 0; p < 8; ++p) {                    // async stage A and W tiles
        int id = t + 256 * p, r = id >> 4, cc = id & 15;
        int c8 = cc ^ (r & 15);                      // XOR swizzle on global side
        gload_lds16(A + (row0 + r) * 256 + aoff + c8 * 8, &As[p * 256 + wv * 64]);
        gload_lds16(Wg + r * CH + c8 * 8,                 &Bs[p * 256 + wv * 64]);
    }
    __syncthreads();                                 // vmcnt(0) drain at barrier

    const int l = t & 63;
    const int m0 = (wv >> 1) * 64, n0 = (wv & 1) * 64;
    const int lm = l & 15, q = l >> 4;
    f32x4 acc[4][4];
    #pragma unroll
    for (int i = 0; i < 4; ++i)
        #pragma unroll
        for (int j = 0; j < 4; ++j) { acc[i][j][0]=0.f; acc[i][j][1]=0.f; acc[i][j][2]=0.f; acc[i][j][3]=0.f; }

    #pragma unroll
    for (int kc = 0; kc < 4; ++kc) {
        int c8 = kc * 4 + q;
        bf16x8 a[4], b[4];
        #pragma unroll
        for (int i = 0; i < 4; ++i) { int r = m0 + i * 16 + lm; a[i] = *(const bf16x8*)&As[SWZ(r, c8)]; }
        #pragma unroll
        for (int j = 0; j < 4; ++j) { int r = n0 + j * 16 + lm; b[j] = *(const bf16x8*)&Bs[SWZ(r, c8)]; }
        #pragma unroll
        for (int i = 0; i < 4; ++i)
            #pragma unroll
            for (int j = 0; j < 4; ++j)
                acc[i][j] = __builtin_amdgcn_mfma_f32_16x16x32_bf16(a[i], b[j], acc[i][j], 0, 0, 0);
    }

    #pragma unroll
    for (int j = 0; j < 4; ++j) {
        float bb = bias[g * CH + n0 + j * 16 + lm];
        #pragma unroll
        for (int i = 0; i < 4; ++i)
            #pragma unroll
            for (int r = 0; r < 4; ++r) {
                int rowl = m0 + i * 16 + q * 4 + r;   // C/D: row=(lane>>4)*4+reg
                int col  = n0 + j * 16 + lm;          //      col=lane&15
                out[(row0 + rowl) * GC + g * CH + col] = f2bf(fmaxf(acc[i][j][r] + bb, 0.f));
            }
    }
}

// ---------- 7. GEMM2 (fused): Sb = dis .* (h0x@Wx1 + h0h@Wh1) -> bf16 [NP,512] ----------
// LINEAR output layout (round-0 validated); gate interleave no longer needed
// since LSTM lives in k_lstm now.
__global__ __launch_bounds__(256) void k_gemm2(
        const unsigned short* __restrict__ A1, const unsigned short* __restrict__ A2,
        const unsigned short* __restrict__ Wt1, const unsigned short* __restrict__ Wt2,
        const float* __restrict__ dis, unsigned short* __restrict__ outS) {
    __shared__ uint4 As[2048];
    __shared__ uint4 Bs[2048];
    const int    g    = blockIdx.y;
    const size_t row0 = (size_t)blockIdx.x * 128;
    const int    t    = threadIdx.x;
    const int    wv   = t >> 6;
    const int l = t & 63;
    const int m0 = (wv >> 1) * 64, n0 = (wv & 1) * 64;
    const int lm = l & 15, q = l >> 4;
    f32x4 acc[4][4];
    #pragma unroll
    for (int i = 0; i < 4; ++i)
        #pragma unroll
        for (int j = 0; j < 4; ++j) { acc[i][j][0]=0.f; acc[i][j][1]=0.f; acc[i][j][2]=0.f; acc[i][j][3]=0.f; }

    for (int side = 0; side < 2; ++side) {
        if (side) __syncthreads();                   // all waves done reading LDS
        const unsigned short* Ap = side ? A2 : A1;
        const unsigned short* Wg = (side ? Wt2 : Wt1) + (size_t)g * 16384;
        #pragma unroll
        for (int p = 0; p < 8; ++p) {                // async stage A and W tiles
            int id = t + 256 * p, r = id >> 4, cc = id & 15;
            int c8 = cc ^ (r & 15);
            gload_lds16(Ap + (row0 + r) * GC + g * CH + c8 * 8, &As[p * 256 + wv * 64]);
            gload_lds16(Wg + r * CH + c8 * 8,                   &Bs[p * 256 + wv * 64]);
        }
        __syncthreads();
        #pragma unroll
        for (int kc = 0; kc < 4; ++kc) {
            int c8 = kc * 4 + q;
            bf16x8 a[4], b[4];
            #pragma unroll
            for (int i = 0; i < 4; ++i) { int r = m0 + i * 16 + lm; a[i] = *(const bf16x8*)&As[SWZ(r, c8)]; }
            #pragma unroll
            for (int j = 0; j < 4; ++j) { int r = n0 + j * 16 + lm; b[j] = *(const bf16x8*)&Bs[SWZ(r, c8)]; }
            #pragma unroll
            for (int i = 0; i < 4; ++i)
                #pragma unroll
                for (int j = 0; j < 4; ++j)
                    acc[i][j] = __builtin_amdgcn_mfma_f32_16x16x32_bf16(a[i], b[j], acc[i][j], 0, 0, 0);
        }
    }

    #pragma unroll
    for (int j = 0; j < 4; ++j)
        #pragma unroll
        for (int i = 0; i < 4; ++i)
            #pragma unroll
            for (int r = 0; r < 4; ++r) {
                int rowl = m0 + i * 16 + q * 4 + r;
                int col  = n0 + j * 16 + lm;
                float dr = dis[row0 + rowl];         // pre-scale for prop
                outS[(row0 + rowl) * GC + g * CH + col] = f2bf(dr * acc[i][j][r]);
            }
}

// ---------- 8. XCD-chunked prop, 8 NODES/WAVE -> fp32 Gbuf (NO LSTM) ----------
// chunk = bid&7 == XCD; per-XCD gather footprint = NP*128B = 2.57 MB (L2-fit).
// Same structure as k_prop256m; 1 KB rows (64 uint4), fp32 output.
__global__ __launch_bounds__(256) void k_prop512m(
        const unsigned short* __restrict__ Sb, float* __restrict__ Gbuf,
        const int* __restrict__ rowoff, const int* __restrict__ csrs,
        const float* __restrict__ csrw, const float* __restrict__ dis) {
    int chunk = blockIdx.x & 7;
    int wbase = (blockIdx.x >> 3) * 32 + (threadIdx.x >> 6) * 8;  // grid: (NN/32)*8
    int l = threadIdx.x & 63, grp = l >> 3, li = l & 7;
    int w = wbase + grp;
    const uint4* S4 = (const uint4*)Sb;              // row = 64 uint4 = 1 KB
    int coff = chunk * 8 + li;
    float acc[8];
    tof8(S4[(size_t)w * 64 + coff], acc);            // self term (every lane)
    int e0 = rowoff[w], deg = rowoff[w + 1] - e0;
    int md = deg;                                    // wave-max degree (bits 3..5)
    md = max(md, __shfl_xor(md, 8));
    md = max(md, __shfl_xor(md, 16));
    md = max(md, __shfl_xor(md, 32));
    int k = 0;
    for (; k + 2 <= md; k += 2) {
        bool a0 = k < deg, a1 = k + 1 < deg;
        int i0 = a0 ? e0 + k : 0, i1 = a1 ? e0 + k + 1 : 0;
        int s0 = csrs[i0], s1 = csrs[i1];
        float n0 = a0 ? csrw[i0] : 0.f;
        float n1 = a1 ? csrw[i1] : 0.f;
        uint4 u0 = S4[(size_t)s0 * 64 + coff];
        uint4 u1 = S4[(size_t)s1 * 64 + coff];
        fma8(u0, n0, acc); fma8(u1, n1, acc);
    }
    if (k < md) {
        bool a = k < deg;
        int i0 = a ? e0 + k : 0;
        int s = csrs[i0]; float n = a ? csrw[i0] : 0.f;
        fma8(S4[(size_t)s * 64 + coff], n, acc);
    }
    float dw = dis[w];
    #pragma unroll
    for (int j = 0; j < 8; ++j) acc[j] *= dw;
    float* gp = Gbuf + (size_t)w * GC + chunk * 64 + li * 8;
    *(float4*)gp       = *(float4*)&acc[0];
    *(float4*)(gp + 4) = *(float4*)&acc[4];
}

// ---------- 9. LSTM gate kernel: 1 thread per (node, feature), plain Gbuf ----------
__global__ __launch_bounds__(256) void k_lstm(
        const float* __restrict__ Gbuf, const float* __restrict__ c,
        const float* __restrict__ btot, const float* __restrict__ wc,
        float* __restrict__ out) {
    int t = threadIdx.x;
    int w = blockIdx.x * 2 + (t >> 7);               // grid exact: NN/2
    int hh = t & 127;
    const float* gr = Gbuf + (size_t)w * GC;
    float g0 = gr[hh]       + btot[hh];
    float g1 = gr[128 + hh] + btot[128 + hh];
    float g2 = gr[256 + hh] + btot[256 + hh];
    float g3 = gr[384 + hh] + btot[384 + hh];
    float cv = c[(size_t)w * CH + hh];
    float I  = 1.f / (1.f + expf(-(g0 + wc[hh]       * cv)));
    float F  = 1.f / (1.f + expf(-(g1 + wc[128 + hh] * cv)));
    float T  = tanhf(g2);
    float Cn = F * cv + I * T;
    float O  = 1.f / (1.f + expf(-(g3 + wc[256 + hh] * Cn)));
    out[(size_t)w * CH + hh]         = O * tanhf(Cn);   // Hn
    out[NHtot + (size_t)w * CH + hh] = Cn;              // Cn
}

extern "C" void kernel_launch(void* const* d_in, const int* in_sizes, int n_in,
                              void* d_out, int out_size, void* d_ws, size_t ws_size,
                              hipStream_t stream) {
    (void)in_sizes; (void)n_in; (void)out_size; (void)ws_size;
    const float* x   = (const float*)d_in[0];
    const int*   ei  = (const int*)d_in[1];
    const float* ew  = (const float*)d_in[2];
    const float* h   = (const float*)d_in[3];
    const float* c   = (const float*)d_in[4];
    const float* Wx0 = (const float*)d_in[5];
    const float* bx0 = (const float*)d_in[6];
    const float* Wx1 = (const float*)d_in[7];
    const float* bx1 = (const float*)d_in[8];
    const float* Wh0 = (const float*)d_in[9];
    const float* bh0 = (const float*)d_in[10];
    const float* Wh1 = (const float*)d_in[11];
    const float* bh1 = (const float*)d_in[12];
    const float* wc  = (const float*)d_in[13];
    const float* bg  = (const float*)d_in[14];
    float* out = (float*)d_out;

    // Workspace layout (float units).
    float* wsf  = (float*)d_ws;
    float* dis  = wsf;                                  // [20480]
    int*   cnt  = (int*)(wsf + 20480);                  // [20480]  zeroed
    int*   row  = (int*)(wsf + 40960);                  // [20736]
    int*   cur  = (int*)(wsf + 61696);                  // [20480]
    int*   bsum = (int*)(wsf + 82176);                  // [256]
    float* btot = wsf + 82432;                          // [512]
    int*   csrs = (int*)(wsf + 82944);                  // [E]
    float* csrw = wsf + 402944;                         // [E] raw weights
    unsigned short* Wt0x = (unsigned short*)(wsf + 722944);   // +32768 floats each
    unsigned short* Wt0h = (unsigned short*)(wsf + 755712);
    unsigned short* Wt1x = (unsigned short*)(wsf + 788480);
    unsigned short* Wt1h = (unsigned short*)(wsf + 821248);
    unsigned short* xhb  = (unsigned short*)(wsf + 854016);   // [NP*256] bf16
    unsigned short* axh  = (unsigned short*)(wsf + 3426304);  // [NP*256] bf16
    unsigned short* h0x  = (unsigned short*)(wsf + 5998592);  // [NP*512] bf16
    unsigned short* h0h  = (unsigned short*)(wsf + 11143168); // [NP*512] bf16
    unsigned short* Sb   = (unsigned short*)(wsf + 16287744); // [NP*512] bf16
    // Gbuf fp32 [NP*512] REUSES the h0x+h0h region (dead after k_gemm2):
    // 5998592 + NP*512 = 16287744 exactly -> no overlap with Sb.
    float* Gbuf = wsf + 5998592;

    hipMemsetAsync(cnt, 0, 20480 * sizeof(int), stream);

    k_cntprep<<<EE / 256 + 1024, 256, 0, stream>>>(ei, cnt,
                                                   Wx0, Wh0, Wx1, Wh1,
                                                   Wt0x, Wt0h, Wt1x, Wt1h,
                                                   bx1, bh1, bg, btot);
    k_scan1  <<<80, 256, 0, stream>>>(cnt, row, bsum);
    k_scan2  <<<1, 64, 0, stream>>>(bsum);
    k_scan3  <<<80, 256, 0, stream>>>(row, bsum, cur);
    k_scatter<<<EE / 256, 256, 0, stream>>>(ei, ew, cur, csrs, csrw);

    k_degcast<<<NN / 4, 256, 0, stream>>>(x, h, row, csrw, dis, xhb);

    k_prop256m<<<(NN / 32) * 4, 256, 0, stream>>>(xhb, axh, row, csrs, csrw, dis);

    dim3 g1(NP / 128, 4, 2);
    k_gemm1<<<g1, 256, 0, stream>>>(axh, Wt0x, Wt0h, bx0, bh0, h0x, h0h);
    dim3 g2(NP / 128, 4);
    k_gemm2<<<g2, 256, 0, stream>>>(h0x, h0h, Wt1x, Wt1h, dis, Sb);

    k_prop512m<<<(NN / 32) * 8, 256, 0, stream>>>(Sb, Gbuf, row, csrs, csrw, dis);
    k_lstm<<<NN / 2, 256, 0, stream>>>(Gbuf, c, btot, wc, out);
}

// Round 7
// 256.881 us; speedup vs baseline: 1.6740x; 1.0083x over previous
//
#include <hip/hip_runtime.h>
#include <hip/hip_bf16.h>
#include <stdint.h>

// Problem constants (fixed by the reference)
#define NN    20000      // nodes
#define NP    20096      // nodes padded to 157*128 (garbage rows never read back)
#define EE    320000     // edges (w/o self loops)
#define CH    128        // feature width per gate
#define GC    512        // 4 gates * 128
#define NHtot 2560000    // N*CH

typedef short bf16x8 __attribute__((ext_vector_type(8)));   // 8 bf16 (4 VGPRs)
typedef float f32x4  __attribute__((ext_vector_type(4)));   // 4 fp32 acc

// ---------- bf16 helpers ----------
__device__ __forceinline__ unsigned short f2bf(float f) {
    __hip_bfloat16 b = __float2bfloat16(f);           // RNE
    union { __hip_bfloat16 b; unsigned short u; } c; c.b = b; return c.u;
}
// fast bf16x2 dword -> two f32: lo = u<<16, hi = u & 0xffff0000 (1 VALU op each)
__device__ __forceinline__ void fma8(uint4 u, float n, float* acc) {
    union { unsigned int i; float f; } t;
    t.i = u.x << 16;         acc[0] += n * t.f;
    t.i = u.x & 0xffff0000u; acc[1] += n * t.f;
    t.i = u.y << 16;         acc[2] += n * t.f;
    t.i = u.y & 0xffff0000u; acc[3] += n * t.f;
    t.i = u.z << 16;         acc[4] += n * t.f;
    t.i = u.z & 0xffff0000u; acc[5] += n * t.f;
    t.i = u.w << 16;         acc[6] += n * t.f;
    t.i = u.w & 0xffff0000u; acc[7] += n * t.f;
}
__device__ __forceinline__ void tof8(uint4 u, float* f) {
    union { unsigned int i; float f; } t;
    t.i = u.x << 16;         f[0] = t.f;
    t.i = u.x & 0xffff0000u; f[1] = t.f;
    t.i = u.y << 16;         f[2] = t.f;
    t.i = u.y & 0xffff0000u; f[3] = t.f;
    t.i = u.z << 16;         f[4] = t.f;
    t.i = u.z & 0xffff0000u; f[5] = t.f;
    t.i = u.w << 16;         f[6] = t.f;
    t.i = u.w & 0xffff0000u; f[7] = t.f;
}
__device__ __forceinline__ uint2 pack4(const float* f) {
    uint2 v;
    v.x = (unsigned int)f2bf(f[0]) | ((unsigned int)f2bf(f[1]) << 16);
    v.y = (unsigned int)f2bf(f[2]) | ((unsigned int)f2bf(f[3]) << 16);
    return v;
}
__device__ __forceinline__ uint4 pack8(const float* f) {
    uint4 v;
    v.x = (unsigned int)f2bf(f[0]) | ((unsigned int)f2bf(f[1]) << 16);
    v.y = (unsigned int)f2bf(f[2]) | ((unsigned int)f2bf(f[3]) << 16);
    v.z = (unsigned int)f2bf(f[4]) | ((unsigned int)f2bf(f[5]) << 16);
    v.w = (unsigned int)f2bf(f[6]) | ((unsigned int)f2bf(f[7]) << 16);
    return v;
}
// async 16B global -> LDS (lane deposits at lds_base + lane*16)
__device__ __forceinline__ void gload_lds16(const void* g, void* l) {
    __builtin_amdgcn_global_load_lds(
        (const __attribute__((address_space(1))) void*)g,
        (__attribute__((address_space(3))) void*)l, 16, 0, 0);
}

// ---------- 1. MERGED: edge count (int atomics) + weight prep + btot ----------
__global__ void k_cntprep(const int* __restrict__ ei, int* __restrict__ cnt,
                          const float* __restrict__ W0, const float* __restrict__ W1,
                          const float* __restrict__ W2, const float* __restrict__ W3,
                          unsigned short* __restrict__ T0, unsigned short* __restrict__ T1,
                          unsigned short* __restrict__ T2, unsigned short* __restrict__ T3,
                          const float* __restrict__ bx1, const float* __restrict__ bh1,
                          const float* __restrict__ bg, float* __restrict__ btot) {
    int bid = blockIdx.x;
    if (bid < EE / 256) {
        int e = bid * 256 + threadIdx.x;
        atomicAdd(&cnt[ei[EE + e]], 1);
        return;
    }
    int pid = bid - EE / 256;                        // 0..1023
    int z = pid >> 8, y = (pid >> 6) & 3, xb = pid & 63;
    if (z == 0 && y == 0 && xb < 2) {
        int f = xb * 256 + threadIdx.x;              // 512 entries, f = g*128+hh
        btot[f] = bx1[f] + bh1[f] + bg[f];
    }
    const float* W; unsigned short* T;
    switch (z) {
        case 0:  W = W0; T = T0; break;
        case 1:  W = W1; T = T1; break;
        case 2:  W = W2; T = T2; break;
        default: W = W3; T = T3; break;
    }
    int n = xb * 2 + (threadIdx.x >> 7);
    int k = threadIdx.x & 127;
    T[((size_t)y * 128 + n) * 128 + k] = f2bf(W[((size_t)y * 128 + k) * 128 + n]);
}

// ---------- 2. hierarchical exclusive scan of counts ----------
__global__ void k_scan1(const int* __restrict__ cnt, int* __restrict__ rowoff,
                        int* __restrict__ bsum) {
    __shared__ int wsum[4];
    int i = blockIdx.x * 256 + threadIdx.x;
    int self = (i < NN) ? cnt[i] : 0;
    int lane = threadIdx.x & 63, wid = threadIdx.x >> 6;
    int v = self;
    #pragma unroll
    for (int off = 1; off < 64; off <<= 1) {
        int u = __shfl_up(v, off);
        if (lane >= off) v += u;
    }
    if (lane == 63) wsum[wid] = v;
    __syncthreads();
    int wof = 0;
    for (int k = 0; k < wid; ++k) wof += wsum[k];
    if (i < NN) rowoff[i] = wof + v - self;
    if (threadIdx.x == 255) bsum[blockIdx.x] = wof + v;
}

__global__ void k_scan2(int* __restrict__ bsum) {
    int lane = threadIdx.x;                          // 64 threads
    int base = 0;
    for (int start = 0; start < 80; start += 64) {
        int i = start + lane;
        int self = (i < 80) ? bsum[i] : 0;
        int v = self;
        #pragma unroll
        for (int off = 1; off < 64; off <<= 1) {
            int u = __shfl_up(v, off);
            if (lane >= off) v += u;
        }
        if (i < 80) bsum[i] = base + v - self;
        base += __shfl(v, 63);
    }
}

__global__ void k_scan3(int* __restrict__ rowoff, const int* __restrict__ bsum,
                        int* __restrict__ cur) {
    int i = blockIdx.x * 256 + threadIdx.x;
    if (i < NN) {
        int v = rowoff[i] + bsum[i >> 8];
        rowoff[i] = v; cur[i] = v;
    }
    if (i == NN) rowoff[NN] = EE;
}

// ---------- 3. scatter edges into PACKED int2 CSR {src, weight-bits} ----------
// One 8-B random store per edge (was two 4-B stores to separate arrays).
__global__ void k_scatter(const int* __restrict__ ei, const float* __restrict__ ew,
                          int* __restrict__ cur, int2* __restrict__ csre) {
    int e = blockIdx.x * 256 + threadIdx.x;
    if (e >= EE) return;
    int s = ei[e], d = ei[EE + e];
    int p = atomicAdd(&cur[d], 1);
    csre[p] = make_int2(s, __float_as_int(ew[e]));
}

// ---------- 4. FUSED: degree row-sum -> dis -> scale & pack x|h to bf16 ----------
__global__ __launch_bounds__(256) void k_degcast(
        const float* __restrict__ x, const float* __restrict__ h,
        const int* __restrict__ rowoff, const int2* __restrict__ csre,
        float* __restrict__ dis, unsigned short* __restrict__ xhb) {
    int wid = threadIdx.x >> 6, lane = threadIdx.x & 63;
    int w = blockIdx.x * 4 + wid;                    // grid exact: NN/4
    int e0 = rowoff[w], e1 = rowoff[w + 1];
    float s = 0.f;
    for (int e = e0 + lane; e < e1; e += 64) s += __int_as_float(csre[e].y);
    #pragma unroll
    for (int off = 32; off; off >>= 1) s += __shfl_xor(s, off);
    float dn = rsqrtf(fmaxf(1.0f + s, 1e-12f));      // self-loop weight 1
    if (lane == 0) dis[w] = dn;
    const float* src = (lane < 32) ? x + (size_t)w * CH + lane * 4
                                   : h + (size_t)w * CH + (lane - 32) * 4;
    float4 v = *(const float4*)src;
    float f[4] = { dn * v.x, dn * v.y, dn * v.z, dn * v.w };
    *(uint2*)(xhb + (size_t)w * 256 + lane * 4) = pack4(f);
}

// ---------- 5. XCD-chunked prop, 8 NODES/WAVE, serial edges, NO reduce ----------
// chunk = bid&3 (128 B slice of the 512 B row) -> per-XCD footprint 2.57 MB.
// Wave = 8 nodes x 8 lanes; lane owns (node grp, 16B slice li), privately
// accumulates its 8 features over the node's edge list. Loop = wave-max degree,
// branch-free predication: inactive slots read csre[0] with weight 0 (row 0 is
// a valid node -> safe gather). x4 unroll: 4 independent csre->gather->fma
// chains in flight (R6 had 2).
__global__ __launch_bounds__(256) void k_prop256m(
        const unsigned short* __restrict__ tab, unsigned short* __restrict__ o,
        const int* __restrict__ rowoff, const int2* __restrict__ csre,
        const float* __restrict__ dis) {
    int chunk = blockIdx.x & 3;
    int wbase = (blockIdx.x >> 2) * 32 + (threadIdx.x >> 6) * 8;  // grid: (NN/32)*4
    int l = threadIdx.x & 63, grp = l >> 3, li = l & 7;
    int w = wbase + grp;
    const uint4* T4 = (const uint4*)tab;             // row = 32 uint4 = 512 B
    int coff = chunk * 8 + li;
    float acc[8];
    tof8(T4[(size_t)w * 32 + coff], acc);            // self term (every lane)
    int e0 = rowoff[w], deg = rowoff[w + 1] - e0;
    int md = deg;                                    // wave-max degree (bits 3..5)
    md = max(md, __shfl_xor(md, 8));
    md = max(md, __shfl_xor(md, 16));
    md = max(md, __shfl_xor(md, 32));
    int k = 0;
    for (; k + 4 <= md; k += 4) {
        int2 p0 = csre[k     < deg ? e0 + k     : 0];
        int2 p1 = csre[k + 1 < deg ? e0 + k + 1 : 0];
        int2 p2 = csre[k + 2 < deg ? e0 + k + 2 : 0];
        int2 p3 = csre[k + 3 < deg ? e0 + k + 3 : 0];
        uint4 u0 = T4[(size_t)p0.x * 32 + coff];
        uint4 u1 = T4[(size_t)p1.x * 32 + coff];
        uint4 u2 = T4[(size_t)p2.x * 32 + coff];
        uint4 u3 = T4[(size_t)p3.x * 32 + coff];
        float n0 = (k     < deg) ? __int_as_float(p0.y) : 0.f;
        float n1 = (k + 1 < deg) ? __int_as_float(p1.y) : 0.f;
        float n2 = (k + 2 < deg) ? __int_as_float(p2.y) : 0.f;
        float n3 = (k + 3 < deg) ? __int_as_float(p3.y) : 0.f;
        fma8(u0, n0, acc); fma8(u1, n1, acc);
        fma8(u2, n2, acc); fma8(u3, n3, acc);
    }
    for (; k < md; ++k) {
        int2 p = csre[k < deg ? e0 + k : 0];
        float n = (k < deg) ? __int_as_float(p.y) : 0.f;
        fma8(T4[(size_t)p.x * 32 + coff], n, acc);
    }
    float dw = dis[w];
    #pragma unroll
    for (int j = 0; j < 8; ++j) acc[j] *= dw;
    ((uint4*)o)[(size_t)w * 32 + coff] = pack8(acc); // linear layout (gemm1 input)
}

// ---------- MFMA GEMM shared machinery ----------
#define SWZ(r, c8) (((r) << 4) + ((c8) ^ ((r) & 15)))

// ---------- 6. GEMM1 (both sides in one launch via blockIdx.z) ----------
// h0 = relu(axh[:, side] @ W0[g] + b0[g]) -> bf16 [NP,512]
__global__ __launch_bounds__(256) void k_gemm1(
        const unsigned short* __restrict__ A,
        const unsigned short* __restrict__ Wtx, const unsigned short* __restrict__ Wth,
        const float* __restrict__ bx0, const float* __restrict__ bh0,
        unsigned short* __restrict__ outx, unsigned short* __restrict__ outh) {
    __shared__ uint4 As[2048];                       // 32 KB
    __shared__ uint4 Bs[2048];                       // 32 KB
    const int side = blockIdx.z;
    const int aoff = side * 128;
    const unsigned short* Wt = side ? Wth : Wtx;
    const float* bias        = side ? bh0 : bx0;
    unsigned short* out      = side ? outh : outx;

    const int    g    = blockIdx.y;
    const size_t row0 = (size_t)blockIdx.x * 128;
    const int    t    = threadIdx.x;
    const int    wv   = t >> 6;                      // wave id (LDS base uniform)
    const unsigned short* Wg = Wt + (size_t)g * 16384;   // [n][k] bf16

    #pragma unroll
    for (int p = 0; p < 8; ++p) {                    // async stage A and W tiles
        int id = t + 256 * p, r = id >> 4, cc = id & 15;
        int c8 = cc ^ (r & 15);                      // XOR swizzle on global side
        gload_lds16(A + (row0 + r) * 256 + aoff + c8 * 8, &As[p * 256 + wv * 64]);
        gload_lds16(Wg + r * CH + c8 * 8,                 &Bs[p * 256 + wv * 64]);
    }
    __syncthreads();                                 // vmcnt(0) drain at barrier

    const int l = t & 63;
    const int m0 = (wv >> 1) * 64, n0 = (wv & 1) * 64;
    const int lm = l & 15, q = l >> 4;
    f32x4 acc[4][4];
    #pragma unroll
    for (int i = 0; i < 4; ++i)
        #pragma unroll
        for (int j = 0; j < 4; ++j) { acc[i][j][0]=0.f; acc[i][j][1]=0.f; acc[i][j][2]=0.f; acc[i][j][3]=0.f; }

    #pragma unroll
    for (int kc = 0; kc < 4; ++kc) {
        int c8 = kc * 4 + q;
        bf16x8 a[4], b[4];
        #pragma unroll
        for (int i = 0; i < 4; ++i) { int r = m0 + i * 16 + lm; a[i] = *(const bf16x8*)&As[SWZ(r, c8)]; }
        #pragma unroll
        for (int j = 0; j < 4; ++j) { int r = n0 + j * 16 + lm; b[j] = *(const bf16x8*)&Bs[SWZ(r, c8)]; }
        #pragma unroll
        for (int i = 0; i < 4; ++i)
            #pragma unroll
            for (int j = 0; j < 4; ++j)
                acc[i][j] = __builtin_amdgcn_mfma_f32_16x16x32_bf16(a[i], b[j], acc[i][j], 0, 0, 0);
    }

    #pragma unroll
    for (int j = 0; j < 4; ++j) {
        float bb = bias[g * CH + n0 + j * 16 + lm];
        #pragma unroll
        for (int i = 0; i < 4; ++i)
            #pragma unroll
            for (int r = 0; r < 4; ++r) {
                int rowl = m0 + i * 16 + q * 4 + r;   // C/D: row=(lane>>4)*4+reg
                int col  = n0 + j * 16 + lm;          //      col=lane&15
                out[(row0 + rowl) * GC + g * CH + col] = f2bf(fmaxf(acc[i][j][r] + bb, 0.f));
            }
    }
}

// ---------- 7. GEMM2 (fused): Sb = dis .* (h0x@Wx1 + h0h@Wh1) -> bf16 [NP,512] ----------
// LINEAR output layout.
__global__ __launch_bounds__(256) void k_gemm2(
        const unsigned short* __restrict__ A1, const unsigned short* __restrict__ A2,
        const unsigned short* __restrict__ Wt1, const unsigned short* __restrict__ Wt2,
        const float* __restrict__ dis, unsigned short* __restrict__ outS) {
    __shared__ uint4 As[2048];
    __shared__ uint4 Bs[2048];
    const int    g    = blockIdx.y;
    const size_t row0 = (size_t)blockIdx.x * 128;
    const int    t    = threadIdx.x;
    const int    wv   = t >> 6;
    const int l = t & 63;
    const int m0 = (wv >> 1) * 64, n0 = (wv & 1) * 64;
    const int lm = l & 15, q = l >> 4;
    f32x4 acc[4][4];
    #pragma unroll
    for (int i = 0; i < 4; ++i)
        #pragma unroll
        for (int j = 0; j < 4; ++j) { acc[i][j][0]=0.f; acc[i][j][1]=0.f; acc[i][j][2]=0.f; acc[i][j][3]=0.f; }

    for (int side = 0; side < 2; ++side) {
        if (side) __syncthreads();                   // all waves done reading LDS
        const unsigned short* Ap = side ? A2 : A1;
        const unsigned short* Wg = (side ? Wt2 : Wt1) + (size_t)g * 16384;
        #pragma unroll
        for (int p = 0; p < 8; ++p) {                // async stage A and W tiles
            int id = t + 256 * p, r = id >> 4, cc = id & 15;
            int c8 = cc ^ (r & 15);
            gload_lds16(Ap + (row0 + r) * GC + g * CH + c8 * 8, &As[p * 256 + wv * 64]);
            gload_lds16(Wg + r * CH + c8 * 8,                   &Bs[p * 256 + wv * 64]);
        }
        __syncthreads();
        #pragma unroll
        for (int kc = 0; kc < 4; ++kc) {
            int c8 = kc * 4 + q;
            bf16x8 a[4], b[4];
            #pragma unroll
            for (int i = 0; i < 4; ++i) { int r = m0 + i * 16 + lm; a[i] = *(const bf16x8*)&As[SWZ(r, c8)]; }
            #pragma unroll
            for (int j = 0; j < 4; ++j) { int r = n0 + j * 16 + lm; b[j] = *(const bf16x8*)&Bs[SWZ(r, c8)]; }
            #pragma unroll
            for (int i = 0; i < 4; ++i)
                #pragma unroll
                for (int j = 0; j < 4; ++j)
                    acc[i][j] = __builtin_amdgcn_mfma_f32_16x16x32_bf16(a[i], b[j], acc[i][j], 0, 0, 0);
        }
    }

    #pragma unroll
    for (int j = 0; j < 4; ++j)
        #pragma unroll
        for (int i = 0; i < 4; ++i)
            #pragma unroll
            for (int r = 0; r < 4; ++r) {
                int rowl = m0 + i * 16 + q * 4 + r;
                int col  = n0 + j * 16 + lm;
                float dr = dis[row0 + rowl];         // pre-scale for prop
                outS[(row0 + rowl) * GC + g * CH + col] = f2bf(dr * acc[i][j][r]);
            }
}

// ---------- 8. XCD-chunked prop, 8 NODES/WAVE -> fp32 Gbuf (NO LSTM) ----------
// chunk = bid&7 == XCD; per-XCD gather footprint = NP*128B = 2.57 MB (L2-fit).
// Same structure as k_prop256m; 1 KB rows (64 uint4), fp32 output, x4 unroll.
__global__ __launch_bounds__(256) void k_prop512m(
        const unsigned short* __restrict__ Sb, float* __restrict__ Gbuf,
        const int* __restrict__ rowoff, const int2* __restrict__ csre,
        const float* __restrict__ dis) {
    int chunk = blockIdx.x & 7;
    int wbase = (blockIdx.x >> 3) * 32 + (threadIdx.x >> 6) * 8;  // grid: (NN/32)*8
    int l = threadIdx.x & 63, grp = l >> 3, li = l & 7;
    int w = wbase + grp;
    const uint4* S4 = (const uint4*)Sb;              // row = 64 uint4 = 1 KB
    int coff = chunk * 8 + li;
    float acc[8];
    tof8(S4[(size_t)w * 64 + coff], acc);            // self term (every lane)
    int e0 = rowoff[w], deg = rowoff[w + 1] - e0;
    int md = deg;                                    // wave-max degree (bits 3..5)
    md = max(md, __shfl_xor(md, 8));
    md = max(md, __shfl_xor(md, 16));
    md = max(md, __shfl_xor(md, 32));
    int k = 0;
    for (; k + 4 <= md; k += 4) {
        int2 p0 = csre[k     < deg ? e0 + k     : 0];
        int2 p1 = csre[k + 1 < deg ? e0 + k + 1 : 0];
        int2 p2 = csre[k + 2 < deg ? e0 + k + 2 : 0];
        int2 p3 = csre[k + 3 < deg ? e0 + k + 3 : 0];
        uint4 u0 = S4[(size_t)p0.x * 64 + coff];
        uint4 u1 = S4[(size_t)p1.x * 64 + coff];
        uint4 u2 = S4[(size_t)p2.x * 64 + coff];
        uint4 u3 = S4[(size_t)p3.x * 64 + coff];
        float n0 = (k     < deg) ? __int_as_float(p0.y) : 0.f;
        float n1 = (k + 1 < deg) ? __int_as_float(p1.y) : 0.f;
        float n2 = (k + 2 < deg) ? __int_as_float(p2.y) : 0.f;
        float n3 = (k + 3 < deg) ? __int_as_float(p3.y) : 0.f;
        fma8(u0, n0, acc); fma8(u1, n1, acc);
        fma8(u2, n2, acc); fma8(u3, n3, acc);
    }
    for (; k < md; ++k) {
        int2 p = csre[k < deg ? e0 + k : 0];
        float n = (k < deg) ? __int_as_float(p.y) : 0.f;
        fma8(S4[(size_t)p.x * 64 + coff], n, acc);
    }
    float dw = dis[w];
    #pragma unroll
    for (int j = 0; j < 8; ++j) acc[j] *= dw;
    float* gp = Gbuf + (size_t)w * GC + chunk * 64 + li * 8;
    *(float4*)gp       = *(float4*)&acc[0];
    *(float4*)(gp + 4) = *(float4*)&acc[4];
}

// ---------- 9. LSTM gate kernel: 1 thread per (node, feature), plain Gbuf ----------
__global__ __launch_bounds__(256) void k_lstm(
        const float* __restrict__ Gbuf, const float* __restrict__ c,
        const float* __restrict__ btot, const float* __restrict__ wc,
        float* __restrict__ out) {
    int t = threadIdx.x;
    int w = blockIdx.x * 2 + (t >> 7);               // grid exact: NN/2
    int hh = t & 127;
    const float* gr = Gbuf + (size_t)w * GC;
    float g0 = gr[hh]       + btot[hh];
    float g1 = gr[128 + hh] + btot[128 + hh];
    float g2 = gr[256 + hh] + btot[256 + hh];
    float g3 = gr[384 + hh] + btot[384 + hh];
    float cv = c[(size_t)w * CH + hh];
    float I  = 1.f / (1.f + expf(-(g0 + wc[hh]       * cv)));
    float F  = 1.f / (1.f + expf(-(g1 + wc[128 + hh] * cv)));
    float T  = tanhf(g2);
    float Cn = F * cv + I * T;
    float O  = 1.f / (1.f + expf(-(g3 + wc[256 + hh] * Cn)));
    out[(size_t)w * CH + hh]         = O * tanhf(Cn);   // Hn
    out[NHtot + (size_t)w * CH + hh] = Cn;              // Cn
}

extern "C" void kernel_launch(void* const* d_in, const int* in_sizes, int n_in,
                              void* d_out, int out_size, void* d_ws, size_t ws_size,
                              hipStream_t stream) {
    (void)in_sizes; (void)n_in; (void)out_size; (void)ws_size;
    const float* x   = (const float*)d_in[0];
    const int*   ei  = (const int*)d_in[1];
    const float* ew  = (const float*)d_in[2];
    const float* h   = (const float*)d_in[3];
    const float* c   = (const float*)d_in[4];
    const float* Wx0 = (const float*)d_in[5];
    const float* bx0 = (const float*)d_in[6];
    const float* Wx1 = (const float*)d_in[7];
    const float* bx1 = (const float*)d_in[8];
    const float* Wh0 = (const float*)d_in[9];
    const float* bh0 = (const float*)d_in[10];
    const float* Wh1 = (const float*)d_in[11];
    const float* bh1 = (const float*)d_in[12];
    const float* wc  = (const float*)d_in[13];
    const float* bg  = (const float*)d_in[14];
    float* out = (float*)d_out;

    // Workspace layout (float units).
    float* wsf  = (float*)d_ws;
    float* dis  = wsf;                                  // [20480]
    int*   cnt  = (int*)(wsf + 20480);                  // [20480]  zeroed
    int*   row  = (int*)(wsf + 40960);                  // [20736]
    int*   cur  = (int*)(wsf + 61696);                  // [20480]
    int*   bsum = (int*)(wsf + 82176);                  // [256]
    float* btot = wsf + 82432;                          // [512]
    int2*  csre = (int2*)(wsf + 82944);                 // [E] packed {src, w-bits}
    unsigned short* Wt0x = (unsigned short*)(wsf + 722944);   // +32768 floats each
    unsigned short* Wt0h = (unsigned short*)(wsf + 755712);
    unsigned short* Wt1x = (unsigned short*)(wsf + 788480);
    unsigned short* Wt1h = (unsigned short*)(wsf + 821248);
    unsigned short* xhb  = (unsigned short*)(wsf + 854016);   // [NP*256] bf16
    unsigned short* axh  = (unsigned short*)(wsf + 3426304);  // [NP*256] bf16
    unsigned short* h0x  = (unsigned short*)(wsf + 5998592);  // [NP*512] bf16
    unsigned short* h0h  = (unsigned short*)(wsf + 11143168); // [NP*512] bf16
    unsigned short* Sb   = (unsigned short*)(wsf + 16287744); // [NP*512] bf16
    // Gbuf fp32 [NP*512] REUSES the h0x+h0h region (dead after k_gemm2):
    // 5998592 + NP*512 = 16287744 exactly -> no overlap with Sb.
    float* Gbuf = wsf + 5998592;

    hipMemsetAsync(cnt, 0, 20480 * sizeof(int), stream);

    k_cntprep<<<EE / 256 + 1024, 256, 0, stream>>>(ei, cnt,
                                                   Wx0, Wh0, Wx1, Wh1,
                                                   Wt0x, Wt0h, Wt1x, Wt1h,
                                                   bx1, bh1, bg, btot);
    k_scan1  <<<80, 256, 0, stream>>>(cnt, row, bsum);
    k_scan2  <<<1, 64, 0, stream>>>(bsum);
    k_scan3  <<<80, 256, 0, stream>>>(row, bsum, cur);
    k_scatter<<<EE / 256, 256, 0, stream>>>(ei, ew, cur, csre);

    k_degcast<<<NN / 4, 256, 0, stream>>>(x, h, row, csre, dis, xhb);

    k_prop256m<<<(NN / 32) * 4, 256, 0, stream>>>(xhb, axh, row, csre, dis);

    dim3 g1(NP / 128, 4, 2);
    k_gemm1<<<g1, 256, 0, stream>>>(axh, Wt0x, Wt0h, bx0, bh0, h0x, h0h);
    dim3 g2(NP / 128, 4);
    k_gemm2<<<g2, 256, 0, stream>>>(h0x, h0h, Wt1x, Wt1h, dis, Sb);

    k_prop512m<<<(NN / 32) * 8, 256, 0, stream>>>(Sb, Gbuf, row, csre, dis);
    k_lstm<<<NN / 2, 256, 0, stream>>>(Gbuf, c, btot, wc, out);
}